// Round 1
// baseline (11537.216 us; speedup 1.0000x reference)
//
#include <hip/hip_runtime.h>

#define T_SEQ  1132
#define BATCH  128
#define HID    13
#define G4     52          // 4*H
#define NLAYER 100
#define NPIPE  2
#define BP     64          // batch per pipeline
#define CH     4           // timesteps per handoff chunk (T_SEQ % CH == 0)
#define RD     16          // ring depth in timesteps (power of 2, > CH)
#define NCLS   10
#define FEAT   (T_SEQ*HID) // 14716

__device__ __forceinline__ float sigm(float x)  { return 1.0f / (1.0f + __expf(-x)); }
__device__ __forceinline__ float tanhf_(float x){ return 1.0f - 2.0f / (1.0f + __expf(2.0f * x)); }

// Workspace layout:
//   [0, 16KB)                       : int progress flags, one 64B line per (pipe,layer)
//   [16KB, 16KB + ringBytes)        : ring buffers  [pipe][layer][RD][BP*HID] floats
//   [.. , .. + actBytes)            : final-layer activations [T][BATCH*HID] floats
#define FLAG_BYTES (16384)
#define RING_FLOATS_PER_WG ((size_t)RD * BP * HID)   // 13312
#define RING_BYTES ((size_t)NPIPE * NLAYER * RING_FLOATS_PER_WG * 4)

__global__ __launch_bounds__(256) void lstm_pipeline(
    const float* __restrict__ xin,   // [BATCH][T][HID]
    const float* __restrict__ w_ih,  // [L][G4][HID]
    const float* __restrict__ w_hh,  // [L][G4][HID]
    const float* __restrict__ b_ih,  // [L][G4]
    const float* __restrict__ b_hh,  // [L][G4]
    int*   flags,                    // [NPIPE*NLAYER] stride 16 ints
    float* ring,                     // see layout
    float* act)                      // [T][BATCH*HID]
{
  const int wg  = blockIdx.x;
  const int p   = wg / NLAYER;
  const int l   = wg - p * NLAYER;
  const int tid = threadIdx.x;

  __shared__ __align__(16) float sW[64][32];      // [row][0..12]=Wih, [16..28]=Whh, rest 0
  __shared__ float sB[64];
  __shared__ __align__(16) float sX[CH][BP][16];  // x chunk, cols 13..15 = 0
  __shared__ __align__(16) float sH[BP][16];      // h_{t-1}, cols 13..15 = 0
  __shared__ float sC[BP * HID];                  // cell state, flat c = b*13+j
  __shared__ float sG[BP][64];                    // gate preacts [b][g]

  int* myflag   = &flags[(p * NLAYER + l) * 16];
  int* prevflag = &flags[(p * NLAYER + l - 1) * 16];
  int* nextflag = &flags[(p * NLAYER + l + 1) * 16];

  if (tid == 0)
    __hip_atomic_store(myflag, 0, __ATOMIC_RELEASE, __HIP_MEMORY_SCOPE_AGENT);

  // zero LDS (pads must be 0; h0 = c0 = 0 is the correct initial state)
  for (int i = tid; i < 64 * 32;     i += 256) ((float*)sW)[i] = 0.f;
  for (int i = tid; i < CH * BP * 16; i += 256) ((float*)sX)[i] = 0.f;
  for (int i = tid; i < BP * 16;     i += 256) ((float*)sH)[i] = 0.f;
  for (int i = tid; i < BP * HID;    i += 256) sC[i] = 0.f;
  if (tid < 64) sB[tid] = 0.f;
  __syncthreads();

  // stage this layer's weights into LDS (coalesced), biases summed
  for (int i = tid; i < G4 * HID; i += 256) {
    int g = i / HID, k = i - g * HID;
    sW[g][k]      = w_ih[(size_t)l * G4 * HID + i];
    sW[g][16 + k] = w_hh[(size_t)l * G4 * HID + i];
  }
  if (tid < G4) sB[tid] = b_ih[l * G4 + tid] + b_hh[l * G4 + tid];
  __syncthreads();

  // per-lane weight registers: lane = gate row, wave = 16-batch chunk
  const int grow = tid & 63;
  const int bch  = tid >> 6;   // 0..3
  float wv[32];
  #pragma unroll
  for (int q = 0; q < 8; ++q) {
    float4 w4 = *(const float4*)&sW[grow][q * 4];
    wv[q*4+0] = w4.x; wv[q*4+1] = w4.y; wv[q*4+2] = w4.z; wv[q*4+3] = w4.w;
  }
  const float brow = sB[grow];

  // cell-thread mapping: cells c = tid + r*256, c < 832
  const int ncell = (tid < (BP * HID - 3 * 256)) ? 4 : 3;
  int cb[4], cj[4];
  #pragma unroll
  for (int r = 0; r < 4; ++r) {
    int c = tid + r * 256;
    cb[r] = c / HID; cj[r] = c - cb[r] * HID;
  }

  const float* ringprev = ring + (size_t)(p * NLAYER + (l - 1)) * RING_FLOATS_PER_WG;
  float*       ringmine = ring + (size_t)(p * NLAYER + l)       * RING_FLOATS_PER_WG;

  #pragma unroll 1
  for (int t0 = 0; t0 < T_SEQ; t0 += CH) {
    // consumer wait: need producer progress >= t0+CH
    if (tid == 0 && l > 0) {
      while (__hip_atomic_load(prevflag, __ATOMIC_RELAXED, __HIP_MEMORY_SCOPE_AGENT) < t0 + CH)
        __builtin_amdgcn_s_sleep(2);
      (void)__hip_atomic_load(prevflag, __ATOMIC_ACQUIRE, __HIP_MEMORY_SCOPE_AGENT);
    }
    // backpressure: may overwrite ring slots [t0, t0+CH) once consumer progress >= t0+CH-RD
    if (tid == 1 && l < NLAYER - 1 && t0 + CH > RD) {
      while (__hip_atomic_load(nextflag, __ATOMIC_RELAXED, __HIP_MEMORY_SCOPE_AGENT) < t0 + CH - RD)
        __builtin_amdgcn_s_sleep(2);
      (void)__hip_atomic_load(nextflag, __ATOMIC_ACQUIRE, __HIP_MEMORY_SCOPE_AGENT);
    }
    __syncthreads();

    // stage the input chunk into sX
    if (l == 0) {
      for (int i = tid; i < CH * BP * HID; i += 256) {
        int s = i / (BP * HID); int r = i - s * (BP * HID);
        int b = r / HID;        int k = r - b * HID;
        sX[s][b][k] = xin[(size_t)(p * BP + b) * (T_SEQ * HID) + (size_t)(t0 + s) * HID + k];
      }
    } else {
      for (int i = tid; i < CH * BP * HID; i += 256) {
        int s = i / (BP * HID); int r = i - s * (BP * HID);
        int b = r / HID;        int k = r - b * HID;
        int slot = (t0 + s) & (RD - 1);
        sX[s][b][k] = ringprev[(size_t)slot * (BP * HID) + r];
      }
    }
    __syncthreads();

    #pragma unroll 1
    for (int s = 0; s < CH; ++s) {
      // gate GEMM: each lane computes its row's preact for 16 batch elements
      #pragma unroll 4
      for (int bi = 0; bi < 16; ++bi) {
        int b = bch * 16 + bi;
        const float4* xp = (const float4*)&sX[s][b][0];
        const float4* hp = (const float4*)&sH[b][0];
        float acc = brow;
        #pragma unroll
        for (int q = 0; q < 4; ++q) {
          float4 v = xp[q];
          acc += wv[q*4+0]*v.x + wv[q*4+1]*v.y + wv[q*4+2]*v.z + wv[q*4+3]*v.w;
        }
        #pragma unroll
        for (int q = 0; q < 4; ++q) {
          float4 v = hp[q];
          acc += wv[16+q*4+0]*v.x + wv[16+q*4+1]*v.y + wv[16+q*4+2]*v.z + wv[16+q*4+3]*v.w;
        }
        sG[b][grow] = acc;
      }
      __syncthreads();

      // cell update + h store (to ring, or to act for last layer)
      const int t    = t0 + s;
      const int slot = t & (RD - 1);
      float* gout = (l < NLAYER - 1)
                  ? (ringmine + (size_t)slot * (BP * HID))
                  : (act + (size_t)t * (BATCH * HID) + (size_t)p * (BP * HID));
      #pragma unroll
      for (int r = 0; r < 4; ++r) {
        if (r < ncell) {
          int b = cb[r], j = cj[r];
          float gi = sG[b][j];
          float gf = sG[b][13 + j];
          float gg = sG[b][26 + j];
          float go = sG[b][39 + j];
          float cs = sC[tid + r * 256];
          float cn = sigm(gf) * cs + sigm(gi) * tanhf_(gg);
          float hn = sigm(go) * tanhf_(cn);
          sC[tid + r * 256] = cn;
          sH[b][j] = hn;
          gout[tid + r * 256] = hn;
        }
      }
      __syncthreads();
    }

    // publish chunk (layer 99 publishes too: layer 98's backpressure reads it)
    __threadfence();
    __syncthreads();
    if (tid == 0)
      __hip_atomic_store(myflag, t0 + CH, __ATOMIC_RELEASE, __HIP_MEMORY_SCOPE_AGENT);
  }
}

__global__ __launch_bounds__(256) void linear_softmax(
    const float* __restrict__ act,    // [T][BATCH*HID]
    const float* __restrict__ w_lin,  // [NCLS][FEAT]
    const float* __restrict__ b_lin,  // [NCLS]
    float* __restrict__ out)          // [BATCH][NCLS]
{
  const int b   = blockIdx.x;
  const int tid = threadIdx.x;
  float accv[NCLS];
  #pragma unroll
  for (int c = 0; c < NCLS; ++c) accv[c] = 0.f;

  for (int i = tid; i < FEAT; i += 256) {
    int t = i / HID; int j = i - t * HID;
    float a = act[(size_t)t * (BATCH * HID) + b * HID + j];
    #pragma unroll
    for (int c = 0; c < NCLS; ++c)
      accv[c] += a * w_lin[(size_t)c * FEAT + i];
  }

  __shared__ float red[NCLS][256];
  #pragma unroll
  for (int c = 0; c < NCLS; ++c) red[c][tid] = accv[c];
  __syncthreads();
  for (int off = 128; off > 0; off >>= 1) {
    if (tid < off) {
      #pragma unroll
      for (int c = 0; c < NCLS; ++c) red[c][tid] += red[c][tid + off];
    }
    __syncthreads();
  }
  if (tid == 0) {
    float lg[NCLS]; float mx = -1e30f;
    #pragma unroll
    for (int c = 0; c < NCLS; ++c) { lg[c] = red[c][0] + b_lin[c]; mx = fmaxf(mx, lg[c]); }
    float sum = 0.f;
    #pragma unroll
    for (int c = 0; c < NCLS; ++c) { lg[c] = __expf(lg[c] - mx); sum += lg[c]; }
    float inv = 1.0f / sum;
    #pragma unroll
    for (int c = 0; c < NCLS; ++c) out[b * NCLS + c] = lg[c] * inv;
  }
}

extern "C" void kernel_launch(void* const* d_in, const int* in_sizes, int n_in,
                              void* d_out, int out_size, void* d_ws, size_t ws_size,
                              hipStream_t stream) {
  const float* xin  = (const float*)d_in[0];
  const float* wih  = (const float*)d_in[1];
  const float* whh  = (const float*)d_in[2];
  const float* bih  = (const float*)d_in[3];
  const float* bhh  = (const float*)d_in[4];
  const float* wlin = (const float*)d_in[5];
  const float* blin = (const float*)d_in[6];

  char*  ws    = (char*)d_ws;
  int*   flags = (int*)ws;
  float* ring  = (float*)(ws + FLAG_BYTES);
  float* act   = (float*)(ws + FLAG_BYTES + RING_BYTES);

  lstm_pipeline<<<NPIPE * NLAYER, 256, 0, stream>>>(xin, wih, whh, bih, bhh, flags, ring, act);
  linear_softmax<<<BATCH, 256, 0, stream>>>(act, wlin, blin, (float*)d_out);
}

// Round 2
// 8569.534 us; speedup vs baseline: 1.3463x; 1.3463x over previous
//
#include <hip/hip_runtime.h>

#define T_SEQ  1132
#define BATCH  128
#define HID    13
#define G4     52          // 4*H
#define NLAYER 100
#define NPIPE  2
#define BP     64          // batch per pipeline
#define CH     4           // timesteps per handoff chunk
#define RD     16          // ring depth in timesteps (power of 2, > CH)
#define NCLS   10
#define FEAT   (T_SEQ*HID)

#define FLAG_BYTES (16384)
#define RING_FLOATS_PER_WG ((size_t)RD * BP * HID)
#define RING_BYTES ((size_t)NPIPE * NLAYER * RING_FLOATS_PER_WG * 4)

typedef float f32x4 __attribute__((ext_vector_type(4)));
typedef short s16x8 __attribute__((ext_vector_type(8)));

__device__ __forceinline__ float sigm(float x)  { return 1.0f / (1.0f + __expf(-x)); }
__device__ __forceinline__ float tanh_(float x) { return 1.0f - 2.0f / (1.0f + __expf(2.0f * x)); }

// split fp32 into bf16 hi + bf16 lo (truncation; residual <= 2^-16 relative)
__device__ __forceinline__ void bf16split(float x, short& hi, short& lo) {
  union { float f; unsigned u; } a; a.f = x;
  unsigned hu = a.u & 0xFFFF0000u;
  hi = (short)(hu >> 16);
  union { float f; unsigned u; } h; h.u = hu;
  union { float f; unsigned u; } r; r.f = x - h.f;
  lo = (short)(r.u >> 16);
}

__global__ __launch_bounds__(256) void lstm_pipeline(
    const float* __restrict__ xin,   // [BATCH][T][HID]
    const float* __restrict__ w_ih,  // [L][G4][HID]
    const float* __restrict__ w_hh,  // [L][G4][HID]
    const float* __restrict__ b_ih,  // [L][G4]
    const float* __restrict__ b_hh,  // [L][G4]
    int*   flags,
    float* ring,
    float* act)                      // [T][BATCH*HID]
{
  const int wg   = blockIdx.x;
  const int p    = wg / NLAYER;
  const int l    = wg - p * NLAYER;
  const int tid  = threadIdx.x;
  const int lane = tid & 63;
  const int nt   = tid >> 6;          // wave id = N-tile (16 batch)
  const int quad = lane >> 4;         // 0..3
  const int m16  = lane & 15;
  const int nrow = nt * 16 + m16;     // batch column this lane owns in B/D frags

  // bf16 hi/lo images of x chunk and h state, MFMA-B layout: [n][k] k-contiguous
  __shared__ __align__(16) short sXh[CH][BP][16];
  __shared__ __align__(16) short sXl[CH][BP][16];
  __shared__ __align__(16) short sHh[BP][16];
  __shared__ __align__(16) short sHl[BP][16];
  __shared__ __align__(16) float sG[BP][72];   // gate preacts [batch][gate], pad 72
  __shared__ __align__(16) float sBias[64];

  int* myflag   = &flags[(p * NLAYER + l) * 16];
  int* prevflag = &flags[(p * NLAYER + l - 1) * 16];
  int* nextflag = &flags[(p * NLAYER + l + 1) * 16];

  if (tid == 0)
    __hip_atomic_store(myflag, 0, __ATOMIC_RELEASE, __HIP_MEMORY_SCOPE_AGENT);

  // zero LDS (pads must be 0; h0 = 0)
  for (int i = tid; i < CH * BP * 16; i += 256) { ((short*)sXh)[i] = 0; ((short*)sXl)[i] = 0; }
  for (int i = tid; i < BP * 16;      i += 256) { ((short*)sHh)[i] = 0; ((short*)sHl)[i] = 0; }
  if (tid < 64) sBias[tid] = (tid < G4) ? (b_ih[l * G4 + tid] + b_hh[l * G4 + tid]) : 0.f;
  __syncthreads();

  // static A-fragments (weights, hi/lo) + bias init values for the accumulator
  // A layout (16x16x32): A[m = lane&15][k = quad*8 + j]
  s16x8 Ah[4], Al[4];
  f32x4 bias4[4];
  #pragma unroll
  for (int mt = 0; mt < 4; ++mt) {
    int g = mt * 16 + m16;
    #pragma unroll
    for (int j = 0; j < 8; ++j) {
      int k = quad * 8 + j;
      float w = 0.f;
      if (g < G4) {
        if (k < HID)                       w = w_ih[(size_t)(l * G4 + g) * HID + k];
        else if (k >= 16 && k < 16 + HID)  w = w_hh[(size_t)(l * G4 + g) * HID + (k - 16)];
      }
      short hi, lo; bf16split(w, hi, lo);
      Ah[mt][j] = hi; Al[mt][j] = lo;
    }
    bias4[mt] = *(const f32x4*)&sBias[mt * 16 + quad * 4];
  }

  // B-frag lane pointers: quads 0,1 read x (k 0..15), quads 2,3 read h (k 16..31)
  const short* bh0 = (quad < 2) ? &sXh[0][nrow][quad * 8] : &sHh[nrow][(quad - 2) * 8];
  const short* bl0 = (quad < 2) ? &sXl[0][nrow][quad * 8] : &sHl[nrow][(quad - 2) * 8];
  const int sstep = (quad < 2) ? BP * 16 : 0;   // element stride per chunk-step s

  // cell mapping: cells c = tid + r*256, c < 832; cell state in registers
  const int ncell = (tid < (BP * HID - 3 * 256)) ? 4 : 3;
  int cb[4], cj[4]; float cstate[4];
  #pragma unroll
  for (int r = 0; r < 4; ++r) {
    int c = tid + r * 256;
    cb[r] = c / HID; cj[r] = c - cb[r] * HID; cstate[r] = 0.f;
  }

  const float* ringprev = ring + (size_t)(p * NLAYER + (l - 1)) * RING_FLOATS_PER_WG;
  float*       ringmine = ring + (size_t)(p * NLAYER + l)       * RING_FLOATS_PER_WG;

  #pragma unroll 1
  for (int t0 = 0; t0 < T_SEQ; t0 += CH) {
    if (tid == 0 && l > 0) {
      while (__hip_atomic_load(prevflag, __ATOMIC_RELAXED, __HIP_MEMORY_SCOPE_AGENT) < t0 + CH)
        __builtin_amdgcn_s_sleep(2);
      (void)__hip_atomic_load(prevflag, __ATOMIC_ACQUIRE, __HIP_MEMORY_SCOPE_AGENT);
    }
    if (tid == 1 && l < NLAYER - 1 && t0 + CH > RD) {
      while (__hip_atomic_load(nextflag, __ATOMIC_RELAXED, __HIP_MEMORY_SCOPE_AGENT) < t0 + CH - RD)
        __builtin_amdgcn_s_sleep(2);
      (void)__hip_atomic_load(nextflag, __ATOMIC_ACQUIRE, __HIP_MEMORY_SCOPE_AGENT);
    }
    __syncthreads();

    // stage chunk: fp32 -> bf16 hi/lo into sX (k<13 only; pads stay 0)
    if (l == 0) {
      for (int i = tid; i < CH * BP * HID; i += 256) {
        int s = i / (BP * HID); int r = i - s * (BP * HID);
        int b = r / HID;        int k = r - b * HID;
        float v = xin[(size_t)(p * BP + b) * (T_SEQ * HID) + (size_t)(t0 + s) * HID + k];
        short hi, lo; bf16split(v, hi, lo);
        sXh[s][b][k] = hi; sXl[s][b][k] = lo;
      }
    } else {
      for (int i = tid; i < CH * BP * HID; i += 256) {
        int s = i / (BP * HID); int r = i - s * (BP * HID);
        int b = r / HID;        int k = r - b * HID;
        int slot = (t0 + s) & (RD - 1);
        float v = ringprev[(size_t)slot * (BP * HID) + r];
        short hi, lo; bf16split(v, hi, lo);
        sXh[s][b][k] = hi; sXl[s][b][k] = lo;
      }
    }
    __syncthreads();

    #pragma unroll
    for (int s = 0; s < CH; ++s) {
      // ---- gate phase: G = W·[x;h] via split-bf16 MFMA ----
      s16x8 Bh = *(const s16x8*)(bh0 + s * sstep);
      s16x8 Bl = *(const s16x8*)(bl0 + s * sstep);
      #pragma unroll
      for (int mt = 0; mt < 4; ++mt) {
        f32x4 acc = bias4[mt];
        acc = __builtin_amdgcn_mfma_f32_16x16x32_bf16(Ah[mt], Bh, acc, 0, 0, 0);
        acc = __builtin_amdgcn_mfma_f32_16x16x32_bf16(Ah[mt], Bl, acc, 0, 0, 0);
        acc = __builtin_amdgcn_mfma_f32_16x16x32_bf16(Al[mt], Bh, acc, 0, 0, 0);
        // D layout: row(gate) = quad*4+reg, col(batch) = lane&15
        *(f32x4*)&sG[nrow][mt * 16 + quad * 4] = acc;
      }
      __syncthreads();

      // ---- cell phase ----
      const int t    = t0 + s;
      const int slot = t & (RD - 1);
      float* gout = (l < NLAYER - 1)
                  ? (ringmine + (size_t)slot * (BP * HID))
                  : (act + (size_t)t * (BATCH * HID) + (size_t)p * (BP * HID));
      #pragma unroll
      for (int r = 0; r < 4; ++r) {
        if (r < ncell) {
          int b = cb[r], j = cj[r];
          float gi = sG[b][j];
          float gf = sG[b][13 + j];
          float gg = sG[b][26 + j];
          float go = sG[b][39 + j];
          float cn = sigm(gf) * cstate[r] + sigm(gi) * tanh_(gg);
          float hn = sigm(go) * tanh_(cn);
          cstate[r] = cn;
          short hi, lo; bf16split(hn, hi, lo);
          sHh[b][j] = hi; sHl[b][j] = lo;
          gout[tid + r * 256] = hn;
        }
      }
      __syncthreads();
    }

    __threadfence();
    __syncthreads();
    if (tid == 0)
      __hip_atomic_store(myflag, t0 + CH, __ATOMIC_RELEASE, __HIP_MEMORY_SCOPE_AGENT);
  }
}

__global__ __launch_bounds__(256) void linear_softmax(
    const float* __restrict__ act,    // [T][BATCH*HID]
    const float* __restrict__ w_lin,  // [NCLS][FEAT]
    const float* __restrict__ b_lin,
    float* __restrict__ out)          // [BATCH][NCLS]
{
  const int b   = blockIdx.x;
  const int tid = threadIdx.x;
  float accv[NCLS];
  #pragma unroll
  for (int c = 0; c < NCLS; ++c) accv[c] = 0.f;

  for (int i = tid; i < FEAT; i += 256) {
    int t = i / HID; int j = i - t * HID;
    float a = act[(size_t)t * (BATCH * HID) + b * HID + j];
    #pragma unroll
    for (int c = 0; c < NCLS; ++c)
      accv[c] += a * w_lin[(size_t)c * FEAT + i];
  }

  __shared__ float red[NCLS][256];
  #pragma unroll
  for (int c = 0; c < NCLS; ++c) red[c][tid] = accv[c];
  __syncthreads();
  for (int off = 128; off > 0; off >>= 1) {
    if (tid < off) {
      #pragma unroll
      for (int c = 0; c < NCLS; ++c) red[c][tid] += red[c][tid + off];
    }
    __syncthreads();
  }
  if (tid == 0) {
    float lg[NCLS]; float mx = -1e30f;
    #pragma unroll
    for (int c = 0; c < NCLS; ++c) { lg[c] = red[c][0] + b_lin[c]; mx = fmaxf(mx, lg[c]); }
    float sum = 0.f;
    #pragma unroll
    for (int c = 0; c < NCLS; ++c) { lg[c] = __expf(lg[c] - mx); sum += lg[c]; }
    float inv = 1.0f / sum;
    #pragma unroll
    for (int c = 0; c < NCLS; ++c) out[b * NCLS + c] = lg[c] * inv;
  }
}

extern "C" void kernel_launch(void* const* d_in, const int* in_sizes, int n_in,
                              void* d_out, int out_size, void* d_ws, size_t ws_size,
                              hipStream_t stream) {
  const float* xin  = (const float*)d_in[0];
  const float* wih  = (const float*)d_in[1];
  const float* whh  = (const float*)d_in[2];
  const float* bih  = (const float*)d_in[3];
  const float* bhh  = (const float*)d_in[4];
  const float* wlin = (const float*)d_in[5];
  const float* blin = (const float*)d_in[6];

  char*  ws    = (char*)d_ws;
  int*   flags = (int*)ws;
  float* ring  = (float*)(ws + FLAG_BYTES);
  float* act   = (float*)(ws + FLAG_BYTES + RING_BYTES);

  lstm_pipeline<<<NPIPE * NLAYER, 256, 0, stream>>>(xin, wih, whh, bih, bhh, flags, ring, act);
  linear_softmax<<<BATCH, 256, 0, stream>>>(act, wlin, blin, (float*)d_out);
}

// Round 3
// 4048.941 us; speedup vs baseline: 2.8494x; 2.1165x over previous
//
#include <hip/hip_runtime.h>

#define T_SEQ  1132
#define BATCH  128
#define HID    13
#define G4     52          // 4*H
#define NLAYER 100
#define NPIPE  2
#define BP     64          // batch per pipeline
#define BPH    (BP*HID)    // 832
#define CH     4           // timesteps per handoff chunk
#define RD     16          // ring depth in timesteps (power of 2, multiple of CH)
#define NCLS   10
#define FEAT   (T_SEQ*HID)

#define FLAG_BYTES (16384)
#define RING_FLOATS_PER_WG ((size_t)RD * BPH)
#define RING_BYTES ((size_t)NPIPE * NLAYER * RING_FLOATS_PER_WG * 4)

typedef float f32x4 __attribute__((ext_vector_type(4)));
typedef short s16x8 __attribute__((ext_vector_type(8)));

__device__ __forceinline__ float sigm(float x)  { return 1.0f / (1.0f + __expf(-x)); }
__device__ __forceinline__ float tanh_(float x) { return 1.0f - 2.0f / (1.0f + __expf(2.0f * x)); }

// split fp32 into bf16 hi + bf16 lo (truncation; residual <= 2^-16 relative)
__device__ __forceinline__ void bf16split(float x, short& hi, short& lo) {
  union { float f; unsigned u; } a; a.f = x;
  unsigned hu = a.u & 0xFFFF0000u;
  hi = (short)(hu >> 16);
  union { float f; unsigned u; } h; h.u = hu;
  union { float f; unsigned u; } r; r.f = x - h.f;
  lo = (short)(r.u >> 16);
}

__global__ __launch_bounds__(256) void lstm_pipeline(
    const float* __restrict__ xin,   // [BATCH][T][HID]
    const float* __restrict__ w_ih,  // [L][G4][HID]
    const float* __restrict__ w_hh,  // [L][G4][HID]
    const float* __restrict__ b_ih,  // [L][G4]
    const float* __restrict__ b_hh,  // [L][G4]
    int*   flags,
    float* ring,
    float* act)                      // [T][BATCH*HID]
{
  const int wg   = blockIdx.x;
  const int p    = wg / NLAYER;
  const int l    = wg - p * NLAYER;
  const int tid  = threadIdx.x;
  const int lane = tid & 63;
  const int nt   = tid >> 6;          // wave id = N-tile (16 batch)
  const int quad = lane >> 4;         // 0..3
  const int m16  = lane & 15;
  const int nrow = nt * 16 + m16;     // batch column this lane owns in B/D frags

  // bf16 hi/lo images of x chunk and h state, MFMA-B layout: [n][k] k-contiguous
  __shared__ __align__(16) short sXh[CH][BP][16];
  __shared__ __align__(16) short sXl[CH][BP][16];
  __shared__ __align__(16) short sHh[BP][16];
  __shared__ __align__(16) short sHl[BP][16];
  __shared__ __align__(16) float sG[BP][76];   // gate preacts, stride 76 (bank spread, 16B aligned)
  __shared__ __align__(16) float sBias[64];
  __shared__ __align__(16) float sHist[CH][BPH]; // chunk h outputs, flushed once per chunk

  int* myflag   = &flags[(p * NLAYER + l) * 16];
  int* prevflag = &flags[(p * NLAYER + l - 1) * 16];
  int* nextflag = &flags[(p * NLAYER + l + 1) * 16];

  if (tid == 0)
    __hip_atomic_store(myflag, 0, __ATOMIC_RELAXED, __HIP_MEMORY_SCOPE_AGENT);

  // zero LDS (pads must be 0; h0 = 0)
  for (int i = tid; i < CH * BP * 16; i += 256) { ((short*)sXh)[i] = 0; ((short*)sXl)[i] = 0; }
  for (int i = tid; i < BP * 16;      i += 256) { ((short*)sHh)[i] = 0; ((short*)sHl)[i] = 0; }
  if (tid < 64) sBias[tid] = (tid < G4) ? (b_ih[l * G4 + tid] + b_hh[l * G4 + tid]) : 0.f;
  __syncthreads();

  // static A-fragments (weights, hi/lo); A layout (16x16x32): A[m=lane&15][k=quad*8+j]
  s16x8 Ah[4], Al[4];
  f32x4 bias4[4];
  #pragma unroll
  for (int mt = 0; mt < 4; ++mt) {
    int g = mt * 16 + m16;
    #pragma unroll
    for (int j = 0; j < 8; ++j) {
      int k = quad * 8 + j;
      float w = 0.f;
      if (g < G4) {
        if (k < HID)                       w = w_ih[(size_t)(l * G4 + g) * HID + k];
        else if (k >= 16 && k < 16 + HID)  w = w_hh[(size_t)(l * G4 + g) * HID + (k - 16)];
      }
      short hi, lo; bf16split(w, hi, lo);
      Ah[mt][j] = hi; Al[mt][j] = lo;
    }
    bias4[mt] = *(const f32x4*)&sBias[mt * 16 + quad * 4];
  }

  // B-frag lane pointers: quads 0,1 read x (k 0..15), quads 2,3 read h (k 16..31)
  const short* bh0 = (quad < 2) ? &sXh[0][nrow][quad * 8] : &sHh[nrow][(quad - 2) * 8];
  const short* bl0 = (quad < 2) ? &sXl[0][nrow][quad * 8] : &sHl[nrow][(quad - 2) * 8];
  const int sstep = (quad < 2) ? BP * 16 : 0;

  // cell mapping: cells c = tid + r*256, c < 832; cell state in registers
  const int ncell = (tid < (BPH - 3 * 256)) ? 4 : 3;
  int cb[4], cj[4]; float cstate[4];
  #pragma unroll
  for (int r = 0; r < 4; ++r) {
    int c = tid + r * 256;
    cb[r] = c / HID; cj[r] = c - cb[r] * HID; cstate[r] = 0.f;
  }

  const float* ringprev = ring + (size_t)(p * NLAYER + (l - 1)) * RING_FLOATS_PER_WG;
  float*       ringmine = ring + (size_t)(p * NLAYER + l)       * RING_FLOATS_PER_WG;

  #pragma unroll 1
  for (int t0 = 0; t0 < T_SEQ; t0 += CH) {
    if (tid == 0 && l > 0) {
      while (__hip_atomic_load(prevflag, __ATOMIC_RELAXED, __HIP_MEMORY_SCOPE_AGENT) < t0 + CH)
        __builtin_amdgcn_s_sleep(2);
    }
    if (tid == 1 && l < NLAYER - 1 && t0 + CH > RD) {
      while (__hip_atomic_load(nextflag, __ATOMIC_RELAXED, __HIP_MEMORY_SCOPE_AGENT) < t0 + CH - RD)
        __builtin_amdgcn_s_sleep(2);
    }
    __syncthreads();

    // stage chunk: fp32 -> bf16 hi/lo into sX (k<13 only; pads stay 0)
    if (l == 0) {
      for (int i = tid; i < CH * BPH; i += 256) {
        int s = i / BPH; int r = i - s * BPH;
        int b = r / HID; int k = r - b * HID;
        float v = xin[(size_t)(p * BP + b) * (T_SEQ * HID) + (size_t)(t0 + s) * HID + k];
        short hi, lo; bf16split(v, hi, lo);
        sXh[s][b][k] = hi; sXl[s][b][k] = lo;
      }
    } else {
      const float* src = ringprev + (size_t)(t0 & (RD - 1)) * BPH;  // CH slots contiguous
      for (int i = tid; i < CH * BPH; i += 256) {
        int s = i / BPH; int r = i - s * BPH;
        int b = r / HID; int k = r - b * HID;
        float v = __hip_atomic_load(&src[i], __ATOMIC_RELAXED, __HIP_MEMORY_SCOPE_AGENT);
        short hi, lo; bf16split(v, hi, lo);
        sXh[s][b][k] = hi; sXl[s][b][k] = lo;
      }
    }
    __syncthreads();

    #pragma unroll
    for (int s = 0; s < CH; ++s) {
      // ---- gate phase: G = W·[x;h] via split-bf16 MFMA ----
      s16x8 Bh = *(const s16x8*)(bh0 + s * sstep);
      s16x8 Bl = *(const s16x8*)(bl0 + s * sstep);
      #pragma unroll
      for (int mt = 0; mt < 4; ++mt) {
        f32x4 acc = bias4[mt];
        acc = __builtin_amdgcn_mfma_f32_16x16x32_bf16(Ah[mt], Bh, acc, 0, 0, 0);
        acc = __builtin_amdgcn_mfma_f32_16x16x32_bf16(Ah[mt], Bl, acc, 0, 0, 0);
        acc = __builtin_amdgcn_mfma_f32_16x16x32_bf16(Al[mt], Bh, acc, 0, 0, 0);
        *(f32x4*)&sG[nrow][mt * 16 + quad * 4] = acc;   // row(gate)=quad*4+reg, col(batch)=lane&15
      }
      __syncthreads();

      // ---- cell phase (stores h into LDS only; global flush once per chunk) ----
      #pragma unroll
      for (int r = 0; r < 4; ++r) {
        if (r < ncell) {
          int b = cb[r], j = cj[r];
          float gi = sG[b][j];
          float gf = sG[b][13 + j];
          float gg = sG[b][26 + j];
          float go = sG[b][39 + j];
          float cn = sigm(gf) * cstate[r] + sigm(gi) * tanh_(gg);
          float hn = sigm(go) * tanh_(cn);
          cstate[r] = cn;
          short hi, lo; bf16split(hn, hi, lo);
          sHh[b][j] = hi; sHl[b][j] = lo;
          sHist[s][tid + r * 256] = hn;
        }
      }
      __syncthreads();
    }

    // ---- chunk flush: LDS -> ring (agent-scope write-through, no cache-wide fences) ----
    const float* hist = (const float*)sHist;
    if (l < NLAYER - 1) {
      float* dst = ringmine + (size_t)(t0 & (RD - 1)) * BPH;   // CH slots contiguous
      for (int i = tid; i < CH * BPH; i += 256)
        __hip_atomic_store(&dst[i], hist[i], __ATOMIC_RELAXED, __HIP_MEMORY_SCOPE_AGENT);
    } else {
      for (int i = tid; i < CH * BPH; i += 256) {
        int s = i / BPH; int r = i - s * BPH;
        act[(size_t)(t0 + s) * (BATCH * HID) + (size_t)p * BPH + r] = hist[i];
      }
    }
    asm volatile("s_waitcnt vmcnt(0)" ::: "memory");  // per-wave drain (LLC ack for sc0/sc1 stores)
    __syncthreads();                                   // all waves drained before publish
    if (tid == 0)
      __hip_atomic_store(myflag, t0 + CH, __ATOMIC_RELAXED, __HIP_MEMORY_SCOPE_AGENT);
  }
}

__global__ __launch_bounds__(256) void linear_softmax(
    const float* __restrict__ act,    // [T][BATCH*HID]
    const float* __restrict__ w_lin,  // [NCLS][FEAT]
    const float* __restrict__ b_lin,
    float* __restrict__ out)          // [BATCH][NCLS]
{
  const int b   = blockIdx.x;
  const int tid = threadIdx.x;
  float accv[NCLS];
  #pragma unroll
  for (int c = 0; c < NCLS; ++c) accv[c] = 0.f;

  for (int i = tid; i < FEAT; i += 256) {
    int t = i / HID; int j = i - t * HID;
    float a = act[(size_t)t * (BATCH * HID) + b * HID + j];
    #pragma unroll
    for (int c = 0; c < NCLS; ++c)
      accv[c] += a * w_lin[(size_t)c * FEAT + i];
  }

  __shared__ float red[NCLS][256];
  #pragma unroll
  for (int c = 0; c < NCLS; ++c) red[c][tid] = accv[c];
  __syncthreads();
  for (int off = 128; off > 0; off >>= 1) {
    if (tid < off) {
      #pragma unroll
      for (int c = 0; c < NCLS; ++c) red[c][tid] += red[c][tid + off];
    }
    __syncthreads();
  }
  if (tid == 0) {
    float lg[NCLS]; float mx = -1e30f;
    #pragma unroll
    for (int c = 0; c < NCLS; ++c) { lg[c] = red[c][0] + b_lin[c]; mx = fmaxf(mx, lg[c]); }
    float sum = 0.f;
    #pragma unroll
    for (int c = 0; c < NCLS; ++c) { lg[c] = __expf(lg[c] - mx); sum += lg[c]; }
    float inv = 1.0f / sum;
    #pragma unroll
    for (int c = 0; c < NCLS; ++c) out[b * NCLS + c] = lg[c] * inv;
  }
}

extern "C" void kernel_launch(void* const* d_in, const int* in_sizes, int n_in,
                              void* d_out, int out_size, void* d_ws, size_t ws_size,
                              hipStream_t stream) {
  const float* xin  = (const float*)d_in[0];
  const float* wih  = (const float*)d_in[1];
  const float* whh  = (const float*)d_in[2];
  const float* bih  = (const float*)d_in[3];
  const float* bhh  = (const float*)d_in[4];
  const float* wlin = (const float*)d_in[5];
  const float* blin = (const float*)d_in[6];

  char*  ws    = (char*)d_ws;
  int*   flags = (int*)ws;
  float* ring  = (float*)(ws + FLAG_BYTES);
  float* act   = (float*)(ws + FLAG_BYTES + RING_BYTES);

  lstm_pipeline<<<NPIPE * NLAYER, 256, 0, stream>>>(xin, wih, whh, bih, bhh, flags, ring, act);
  linear_softmax<<<BATCH, 256, 0, stream>>>(act, wlin, blin, (float*)d_out);
}

// Round 4
// 3406.577 us; speedup vs baseline: 3.3867x; 1.1886x over previous
//
#include <hip/hip_runtime.h>
#include <stdint.h>

#define T_SEQ  1132
#define BATCH  128
#define HID    13
#define G4     52          // 4*H
#define NLAYER 100
#define NPIPE  2
#define BP     64          // batch per pipeline
#define BPH    (BP*HID)    // 832
#define WBH    (16*HID)    // 208 = per-wave slice per timestep
#define CH     4           // timesteps per handoff chunk
#define RD     16          // ring depth in timesteps (power of 2, multiple of CH)
#define NCLS   10
#define FEAT   (T_SEQ*HID)

#define FLAG_BYTES 65536
#define RING_U32_PER_WG ((size_t)RD * BPH)
#define RING_BYTES ((size_t)NPIPE * NLAYER * RING_U32_PER_WG * 4)

typedef float f32x4 __attribute__((ext_vector_type(4)));
typedef short s16x8 __attribute__((ext_vector_type(8)));

__device__ __forceinline__ float sigm(float x)  { return 1.0f / (1.0f + __expf(-x)); }
__device__ __forceinline__ float tanh_(float x) { return 1.0f - 2.0f / (1.0f + __expf(2.0f * x)); }

// split fp32 into bf16 hi + bf16 lo (residual), ~16 mantissa bits captured
__device__ __forceinline__ void bf16split(float x, short& hi, short& lo) {
  union { float f; unsigned u; } a; a.f = x;
  unsigned hu = a.u & 0xFFFF0000u;
  hi = (short)(hu >> 16);
  union { float f; unsigned u; } h; h.u = hu;
  union { float f; unsigned u; } r; r.f = x - h.f;
  lo = (short)(r.u >> 16);
}

// Each WAVE is an independent pipeline stage for 16 batch elements of one layer.
// Gate dim pre-permuted: gate' = 16*q + j  <->  original gate q*13 + j (q: i,f,g,o).
// MFMA roles: A = Z^T (A[m=batch][k], lane m=lane&15, k=quad*8+jj)
//             B = W'^T (B[k][n=gate'], lane n=lane&15) -> static registers
//             D[m=batch=quad*4+reg][n=gate'=16q+(lane&15)] -> cell update in-register.
__global__ __launch_bounds__(256) void lstm_pipeline(
    const float* __restrict__ xin,   // [BATCH][T][HID]
    const float* __restrict__ w_ih,  // [L][G4][HID]
    const float* __restrict__ w_hh,  // [L][G4][HID]
    const float* __restrict__ b_ih,  // [L][G4]
    const float* __restrict__ b_hh,  // [L][G4]
    int*      flags,                 // per (p,l,wave), 64B stride
    uint32_t* ring,                  // [p][l][RD][BPH] packed (bf16hi<<16)|bf16lo
    float*    act)                   // [T][BATCH*HID]
{
  const int wg   = blockIdx.x;
  const int p    = wg / NLAYER;
  const int l    = wg - p * NLAYER;
  const int lane = threadIdx.x & 63;
  const int nt   = threadIdx.x >> 6;   // wave id: batch group nt*16..+15
  const int quad = lane >> 4;          // 0..3
  const int j    = lane & 15;          // cell index (valid < 13) / A-frag batch row

  __shared__ __align__(16) short sXh[CH][BP][16];
  __shared__ __align__(16) short sXl[CH][BP][16];
  __shared__ __align__(16) short sHh[BP][16];
  __shared__ __align__(16) short sHl[BP][16];

  int* fl     = flags + (((p * NLAYER + l) * 4) + nt) * 16;
  int* flprev = (l > 0)          ? flags + (((p * NLAYER + l - 1) * 4) + nt) * 16 : flags;
  int* flnext = (l < NLAYER - 1) ? flags + (((p * NLAYER + l + 1) * 4) + nt) * 16 : flags;

  if (lane == 0)
    __hip_atomic_store(fl, 0, __ATOMIC_RELAXED, __HIP_MEMORY_SCOPE_AGENT);

  // zero wave-private LDS slices (pads k=13..15 must stay 0; h0 = 0)
  for (int i = lane; i < CH * 16 * 16; i += 64) {
    int s = i >> 8, r = i & 255;
    sXh[s][nt * 16 + (r >> 4)][r & 15] = 0;
    sXl[s][nt * 16 + (r >> 4)][r & 15] = 0;
  }
  for (int i = lane; i < 16 * 16; i += 64) {
    sHh[nt * 16 + (i >> 4)][i & 15] = 0;
    sHl[nt * 16 + (i >> 4)][i & 15] = 0;
  }

  // static B-fragments (permuted weights, hi/lo) + bias per gate-type
  s16x8 Bh[4], Bl[4];
  float bq[4];
  #pragma unroll
  for (int q = 0; q < 4; ++q) {
    #pragma unroll
    for (int jj = 0; jj < 8; ++jj) {
      int k = quad * 8 + jj;
      float w = 0.f;
      if (j < HID) {
        int g = q * HID + j;   // original gate row
        if (k < HID)                      w = w_ih[(size_t)(l * G4 + g) * HID + k];
        else if (k >= 16 && k < 16 + HID) w = w_hh[(size_t)(l * G4 + g) * HID + (k - 16)];
      }
      short hi, lo; bf16split(w, hi, lo);
      Bh[q][jj] = hi; Bl[q][jj] = lo;
    }
    bq[q] = (j < HID) ? (b_ih[l * G4 + q * HID + j] + b_hh[l * G4 + q * HID + j]) : 0.f;
  }

  float cstate[4] = {0.f, 0.f, 0.f, 0.f};

  const uint32_t* ringprev = ring + (size_t)(p * NLAYER + l - 1) * RING_U32_PER_WG;
  uint32_t*       ringmine = ring + (size_t)(p * NLAYER + l)     * RING_U32_PER_WG;

  #pragma unroll 1
  for (int t0 = 0; t0 < T_SEQ; t0 += CH) {
    // per-wave consumer wait
    if (l > 0) {
      while (__hip_atomic_load(flprev, __ATOMIC_RELAXED, __HIP_MEMORY_SCOPE_AGENT) < t0 + CH)
        __builtin_amdgcn_s_sleep(1);
    }
    // per-wave backpressure
    if (l < NLAYER - 1 && t0 + CH > RD) {
      while (__hip_atomic_load(flnext, __ATOMIC_RELAXED, __HIP_MEMORY_SCOPE_AGENT) < t0 + CH - RD)
        __builtin_amdgcn_s_sleep(1);
    }
    asm volatile("" ::: "memory");

    const int slotbase = t0 & (RD - 1);   // CH slots contiguous (RD % CH == 0)

    // stage wave's x-chunk into LDS
    if (l == 0) {
      for (int i = lane; i < CH * WBH; i += 64) {
        int s = i / WBH, r = i - s * WBH;
        int b16 = r / HID, jj = r - b16 * HID;
        float v = xin[(size_t)(p * BP + nt * 16 + b16) * (T_SEQ * HID) + (size_t)(t0 + s) * HID + jj];
        short hi, lo; bf16split(v, hi, lo);
        sXh[s][nt * 16 + b16][jj] = hi;
        sXl[s][nt * 16 + b16][jj] = lo;
      }
    } else {
      const uint32_t* src = ringprev + (size_t)slotbase * BPH + nt * WBH;
      for (int i = lane; i < CH * WBH; i += 64) {
        int s = i / WBH, r = i - s * WBH;
        int b16 = r / HID, jj = r - b16 * HID;
        uint32_t u = __hip_atomic_load(&src[(size_t)s * BPH + r], __ATOMIC_RELAXED, __HIP_MEMORY_SCOPE_AGENT);
        sXh[s][nt * 16 + b16][jj] = (short)(u >> 16);
        sXl[s][nt * 16 + b16][jj] = (short)(u & 0xFFFFu);
      }
    }
    // no barrier: wave-synchronous LDS, compiler inserts lgkmcnt

    #pragma unroll
    for (int s = 0; s < CH; ++s) {
      const short* ph = (quad < 2) ? &sXh[s][nt * 16 + j][quad * 8] : &sHh[nt * 16 + j][(quad - 2) * 8];
      const short* pl = (quad < 2) ? &sXl[s][nt * 16 + j][quad * 8] : &sHl[nt * 16 + j][(quad - 2) * 8];
      s16x8 Azh = *(const s16x8*)ph;
      s16x8 Azl = *(const s16x8*)pl;

      f32x4 acc[4];
      #pragma unroll
      for (int q = 0; q < 4; ++q) {
        f32x4 a = { bq[q], bq[q], bq[q], bq[q] };
        a = __builtin_amdgcn_mfma_f32_16x16x32_bf16(Azh, Bh[q], a, 0, 0, 0);
        a = __builtin_amdgcn_mfma_f32_16x16x32_bf16(Azh, Bl[q], a, 0, 0, 0);
        a = __builtin_amdgcn_mfma_f32_16x16x32_bf16(Azl, Bh[q], a, 0, 0, 0);
        acc[q] = a;
      }

      if (j < HID) {
        uint32_t pk[4]; float hnv[4];
        #pragma unroll
        for (int r = 0; r < 4; ++r) {
          float gi = acc[0][r], gf = acc[1][r], gg = acc[2][r], go = acc[3][r];
          float cn = sigm(gf) * cstate[r] + sigm(gi) * tanh_(gg);
          cstate[r] = cn;
          float hn = sigm(go) * tanh_(cn);
          short hi, lo; bf16split(hn, hi, lo);
          sHh[nt * 16 + quad * 4 + r][j] = hi;
          sHl[nt * 16 + quad * 4 + r][j] = lo;
          pk[r]  = ((uint32_t)(uint16_t)hi << 16) | (uint32_t)(uint16_t)lo;
          hnv[r] = hn;
        }
        if (l < NLAYER - 1) {
          uint32_t* dst = ringmine + (size_t)(slotbase + s) * BPH + (nt * 16 + quad * 4) * HID + j;
          #pragma unroll
          for (int r = 0; r < 4; ++r)
            __hip_atomic_store(&dst[r * HID], pk[r], __ATOMIC_RELAXED, __HIP_MEMORY_SCOPE_AGENT);
        } else {
          float* dst = act + (size_t)(t0 + s) * (BATCH * HID) + (p * BP + nt * 16 + quad * 4) * HID + j;
          #pragma unroll
          for (int r = 0; r < 4; ++r) dst[r * HID] = hnv[r];
        }
      }
    }

    // drain this wave's ring/act stores, then publish per-wave progress
    asm volatile("s_waitcnt vmcnt(0)" ::: "memory");
    __hip_atomic_store(fl, t0 + CH, __ATOMIC_RELAXED, __HIP_MEMORY_SCOPE_AGENT);
  }
}

__global__ __launch_bounds__(256) void linear_softmax(
    const float* __restrict__ act,    // [T][BATCH*HID]
    const float* __restrict__ w_lin,  // [NCLS][FEAT]
    const float* __restrict__ b_lin,
    float* __restrict__ out)          // [BATCH][NCLS]
{
  const int b   = blockIdx.x;
  const int tid = threadIdx.x;
  float accv[NCLS];
  #pragma unroll
  for (int c = 0; c < NCLS; ++c) accv[c] = 0.f;

  for (int i = tid; i < FEAT; i += 256) {
    int t = i / HID; int jj = i - t * HID;
    float a = act[(size_t)t * (BATCH * HID) + b * HID + jj];
    #pragma unroll
    for (int c = 0; c < NCLS; ++c)
      accv[c] += a * w_lin[(size_t)c * FEAT + i];
  }

  __shared__ float red[NCLS][256];
  #pragma unroll
  for (int c = 0; c < NCLS; ++c) red[c][tid] = accv[c];
  __syncthreads();
  for (int off = 128; off > 0; off >>= 1) {
    if (tid < off) {
      #pragma unroll
      for (int c = 0; c < NCLS; ++c) red[c][tid] += red[c][tid + off];
    }
    __syncthreads();
  }
  if (tid == 0) {
    float lg[NCLS]; float mx = -1e30f;
    #pragma unroll
    for (int c = 0; c < NCLS; ++c) { lg[c] = red[c][0] + b_lin[c]; mx = fmaxf(mx, lg[c]); }
    float sum = 0.f;
    #pragma unroll
    for (int c = 0; c < NCLS; ++c) { lg[c] = __expf(lg[c] - mx); sum += lg[c]; }
    float inv = 1.0f / sum;
    #pragma unroll
    for (int c = 0; c < NCLS; ++c) out[b * NCLS + c] = lg[c] * inv;
  }
}

extern "C" void kernel_launch(void* const* d_in, const int* in_sizes, int n_in,
                              void* d_out, int out_size, void* d_ws, size_t ws_size,
                              hipStream_t stream) {
  const float* xin  = (const float*)d_in[0];
  const float* wih  = (const float*)d_in[1];
  const float* whh  = (const float*)d_in[2];
  const float* bih  = (const float*)d_in[3];
  const float* bhh  = (const float*)d_in[4];
  const float* wlin = (const float*)d_in[5];
  const float* blin = (const float*)d_in[6];

  char*     ws    = (char*)d_ws;
  int*      flags = (int*)ws;
  uint32_t* ring  = (uint32_t*)(ws + FLAG_BYTES);
  float*    act   = (float*)(ws + FLAG_BYTES + RING_BYTES);

  lstm_pipeline<<<NPIPE * NLAYER, 256, 0, stream>>>(xin, wih, whh, bih, bhh, flags, ring, act);
  linear_softmax<<<BATCH, 256, 0, stream>>>(act, wlin, blin, (float*)d_out);
}

// Round 5
// 2130.749 us; speedup vs baseline: 5.4146x; 1.5988x over previous
//
#include <hip/hip_runtime.h>
#include <stdint.h>

#define T_SEQ  1132
#define BATCH  128
#define HID    13
#define G4     52           // 4*H
#define NLAYER 100
#define NPIPE  2
#define BP     64           // batch per pipeline
#define BPH    (BP*HID)     // 832
#define WBH    (16*HID)     // 208 = per-wave slice per timestep
#define CH     4            // timesteps per chunk (T_SEQ % CH == 0)
#define RC     8            // chunk slots in ring
#define RD     (RC*CH)      // 32 timesteps of ring slack
#define NW     13           // u32 per lane per chunk = CH*WBH/64
#define NCLS   10
#define FEAT   (T_SEQ*HID)

#define FLAG_BYTES 65536
#define RING_U32_PER_WG ((size_t)RD * BPH)   // 26624
#define RING_BYTES ((size_t)NPIPE * NLAYER * RING_U32_PER_WG * 4)

typedef float f32x4 __attribute__((ext_vector_type(4)));
typedef short s16x8 __attribute__((ext_vector_type(8)));

__device__ __forceinline__ float sigm(float x)  { return 1.0f / (1.0f + __expf(-x)); }
__device__ __forceinline__ float tanh_(float x) { return 1.0f - 2.0f / (1.0f + __expf(2.0f * x)); }

__device__ __forceinline__ void bf16split(float x, short& hi, short& lo) {
  union { float f; unsigned u; } a; a.f = x;
  unsigned hu = a.u & 0xFFFF0000u;
  hi = (short)(hu >> 16);
  union { float f; unsigned u; } h; h.u = hu;
  union { float f; unsigned u; } r; r.f = x - h.f;
  lo = (short)(r.u >> 16);
}

// Wave-private pipeline stage: each wave = one layer x 16 batch elements.
// Ring layout (chunk-contiguous per wave): [p*L+l][slotc(RC)][wave(4)][CH*WBH u32]
__global__ __launch_bounds__(256) void lstm_pipeline(
    const float* __restrict__ xin,   // [BATCH][T][HID]
    const float* __restrict__ w_ih,  // [L][G4][HID]
    const float* __restrict__ w_hh,  // [L][G4][HID]
    const float* __restrict__ b_ih,  // [L][G4]
    const float* __restrict__ b_hh,  // [L][G4]
    int*      flags,
    uint32_t* ring,
    float*    act)                   // [T][BATCH*HID]
{
  const int wg   = blockIdx.x;
  const int p    = wg / NLAYER;
  const int l    = wg - p * NLAYER;
  const int lane = threadIdx.x & 63;
  const int nt   = threadIdx.x >> 6;   // wave id: batch group nt*16..+15
  const int quad = lane >> 4;
  const int j    = lane & 15;          // gate-within-type / A-frag batch row
  const bool last = (l == NLAYER - 1);

  __shared__ __align__(16) short sXh[2][CH][BP][16];
  __shared__ __align__(16) short sXl[2][CH][BP][16];
  __shared__ __align__(16) short sHh[BP][16];
  __shared__ __align__(16) short sHl[BP][16];
  __shared__ __align__(16) uint32_t sOut[4][CH * WBH];

  int* fl     = flags + (((p * NLAYER + l) * 4) + nt) * 16;
  int* flprev = (l > 0)  ? flags + (((p * NLAYER + l - 1) * 4) + nt) * 16 : flags;
  int* flnext = (!last)  ? flags + (((p * NLAYER + l + 1) * 4) + nt) * 16 : flags;

  if (lane == 0)
    __hip_atomic_store(fl, 0, __ATOMIC_RELAXED, __HIP_MEMORY_SCOPE_AGENT);

  // zero wave slices: both sX buffers fully (pads k=13..15 must stay 0), h0 = 0
  for (int i = lane; i < 2 * CH * 16 * 16; i += 64) {
    int bb = i >> 10, s = (i >> 8) & 3, b16 = (i >> 4) & 15, jj = i & 15;
    sXh[bb][s][nt * 16 + b16][jj] = 0;
    sXl[bb][s][nt * 16 + b16][jj] = 0;
  }
  for (int i = lane; i < 256; i += 64) {
    sHh[nt * 16 + (i >> 4)][i & 15] = 0;
    sHl[nt * 16 + (i >> 4)][i & 15] = 0;
  }

  // static B-fragments (gate' = 16q + j <-> original gate q*13+j), hi/lo + bias
  s16x8 Bh[4], Bl[4];
  float bq[4];
  #pragma unroll
  for (int q = 0; q < 4; ++q) {
    #pragma unroll
    for (int jj = 0; jj < 8; ++jj) {
      int k = quad * 8 + jj;
      float w = 0.f;
      if (j < HID) {
        int g = q * HID + j;
        if (k < HID)                      w = w_ih[(size_t)(l * G4 + g) * HID + k];
        else if (k >= 16 && k < 16 + HID) w = w_hh[(size_t)(l * G4 + g) * HID + (k - 16)];
      }
      short hi, lo; bf16split(w, hi, lo);
      Bh[q][jj] = hi; Bl[q][jj] = lo;
    }
    bq[q] = (j < HID) ? (b_ih[l * G4 + q * HID + j] + b_hh[l * G4 + q * HID + j]) : 0.f;
  }

  float cstate[4] = {0.f, 0.f, 0.f, 0.f};
  int cp = 0, cn = 0;          // cached flag values (monotone)
  bool staged = false;
  uint32_t pfu[NW];
  float    pff[NW];

  const uint32_t* ringprev = ring + (size_t)(p * NLAYER + l - 1) * RING_U32_PER_WG;
  uint32_t*       ringmine = ring + (size_t)(p * NLAYER + l)     * RING_U32_PER_WG;
  const size_t    xbase    = (size_t)(p * BP + nt * 16) * (T_SEQ * HID);

  #pragma unroll 1
  for (int t0 = 0; t0 < T_SEQ; t0 += CH) {
    const int buf   = (t0 >> 2) & 1;
    const int slotc = (t0 >> 2) & (RC - 1);

    // ---- fallback staging of current chunk (pipeline fill / producer behind) ----
    if (!staged) {
      if (l > 0) {
        if (cp < t0 + CH) {
          cp = __hip_atomic_load(flprev, __ATOMIC_RELAXED, __HIP_MEMORY_SCOPE_AGENT);
          while (cp < t0 + CH) {
            __builtin_amdgcn_s_sleep(1);
            cp = __hip_atomic_load(flprev, __ATOMIC_RELAXED, __HIP_MEMORY_SCOPE_AGENT);
          }
        }
        const uint32_t* src = ringprev + (size_t)slotc * (CH * BPH) + nt * (CH * WBH);
        #pragma unroll
        for (int k = 0; k < NW; ++k)
          pfu[k] = __hip_atomic_load(&src[lane + 64 * k], __ATOMIC_RELAXED, __HIP_MEMORY_SCOPE_AGENT);
        #pragma unroll
        for (int k = 0; k < NW; ++k) {
          int i = lane + 64 * k, s = i / WBH, r = i - s * WBH;
          int b16 = r / HID, jj = r - b16 * HID;
          sXh[buf][s][nt * 16 + b16][jj] = (short)(pfu[k] >> 16);
          sXl[buf][s][nt * 16 + b16][jj] = (short)(pfu[k] & 0xFFFFu);
        }
      } else {
        #pragma unroll
        for (int k = 0; k < NW; ++k) {
          int i = lane + 64 * k, s = i / WBH, r = i - s * WBH;
          int b16 = r / HID, jj = r - b16 * HID;
          pff[k] = xin[xbase + (size_t)b16 * (T_SEQ * HID) + (size_t)(t0 + s) * HID + jj];
        }
        #pragma unroll
        for (int k = 0; k < NW; ++k) {
          int i = lane + 64 * k, s = i / WBH, r = i - s * WBH;
          int b16 = r / HID, jj = r - b16 * HID;
          short hi, lo; bf16split(pff[k], hi, lo);
          sXh[buf][s][nt * 16 + b16][jj] = hi;
          sXl[buf][s][nt * 16 + b16][jj] = lo;
        }
      }
    }

    // ---- prefetch next chunk into registers (hidden under compute) ----
    bool pf = false;
    if (t0 + CH < T_SEQ) {
      if (l > 0) {
        if (cp < t0 + 2 * CH)
          cp = __hip_atomic_load(flprev, __ATOMIC_RELAXED, __HIP_MEMORY_SCOPE_AGENT);
        if (cp >= t0 + 2 * CH) {
          const uint32_t* src = ringprev + (size_t)((slotc + 1) & (RC - 1)) * (CH * BPH) + nt * (CH * WBH);
          #pragma unroll
          for (int k = 0; k < NW; ++k)
            pfu[k] = __hip_atomic_load(&src[lane + 64 * k], __ATOMIC_RELAXED, __HIP_MEMORY_SCOPE_AGENT);
          pf = true;
        }
      } else {
        #pragma unroll
        for (int k = 0; k < NW; ++k) {
          int i = lane + 64 * k, s = i / WBH, r = i - s * WBH;
          int b16 = r / HID, jj = r - b16 * HID;
          pff[k] = xin[xbase + (size_t)b16 * (T_SEQ * HID) + (size_t)(t0 + CH + s) * HID + jj];
        }
        pf = true;
      }
    }

    // ---- compute CH steps (wave-private, no barriers) ----
    #pragma unroll
    for (int s = 0; s < CH; ++s) {
      const short* ph = (quad < 2) ? &sXh[buf][s][nt * 16 + j][quad * 8] : &sHh[nt * 16 + j][(quad - 2) * 8];
      const short* pl = (quad < 2) ? &sXl[buf][s][nt * 16 + j][quad * 8] : &sHl[nt * 16 + j][(quad - 2) * 8];
      s16x8 Azh = *(const s16x8*)ph;
      s16x8 Azl = *(const s16x8*)pl;

      f32x4 acc[4];
      #pragma unroll
      for (int q = 0; q < 4; ++q) {
        f32x4 a = { bq[q], bq[q], bq[q], bq[q] };
        a = __builtin_amdgcn_mfma_f32_16x16x32_bf16(Azh, Bh[q], a, 0, 0, 0);
        a = __builtin_amdgcn_mfma_f32_16x16x32_bf16(Azh, Bl[q], a, 0, 0, 0);
        a = __builtin_amdgcn_mfma_f32_16x16x32_bf16(Azl, Bh[q], a, 0, 0, 0);
        acc[q] = a;
      }

      if (j < HID) {
        #pragma unroll
        for (int r = 0; r < 4; ++r) {
          float gi = acc[0][r], gf = acc[1][r], gg = acc[2][r], go = acc[3][r];
          float cn_ = sigm(gf) * cstate[r] + sigm(gi) * tanh_(gg);
          cstate[r] = cn_;
          float hn = sigm(go) * tanh_(cn_);
          short hi, lo; bf16split(hn, hi, lo);
          sHh[nt * 16 + quad * 4 + r][j] = hi;
          sHl[nt * 16 + quad * 4 + r][j] = lo;
          sOut[nt][s * WBH + (quad * 4 + r) * HID + j] =
              last ? __float_as_uint(hn)
                   : (((uint32_t)(uint16_t)hi << 16) | (uint32_t)(uint16_t)lo);
        }
      }
    }

    // ---- backpressure before overwriting ring slot ----
    if (!last && t0 >= RD) {
      int need = t0 + CH - RD;
      if (cn < need) {
        cn = __hip_atomic_load(flnext, __ATOMIC_RELAXED, __HIP_MEMORY_SCOPE_AGENT);
        while (cn < need) {
          __builtin_amdgcn_s_sleep(1);
          cn = __hip_atomic_load(flnext, __ATOMIC_RELAXED, __HIP_MEMORY_SCOPE_AGENT);
        }
      }
    }

    // ---- coalesced chunk flush ----
    if (!last) {
      uint32_t* dst = ringmine + (size_t)slotc * (CH * BPH) + nt * (CH * WBH);
      #pragma unroll
      for (int k = 0; k < NW; ++k)
        __hip_atomic_store(&dst[lane + 64 * k], sOut[nt][lane + 64 * k],
                           __ATOMIC_RELAXED, __HIP_MEMORY_SCOPE_AGENT);
    } else {
      #pragma unroll
      for (int k = 0; k < NW; ++k) {
        int i = lane + 64 * k, s = i / WBH, r = i - s * WBH;
        act[(size_t)(t0 + s) * (BATCH * HID) + (size_t)(p * BP + nt * 16) * HID + r] =
            __uint_as_float(sOut[nt][i]);
      }
    }

    // ---- restage prefetched chunk into the other LDS buffer ----
    if (pf) {
      if (l > 0) {
        #pragma unroll
        for (int k = 0; k < NW; ++k) {
          int i = lane + 64 * k, s = i / WBH, r = i - s * WBH;
          int b16 = r / HID, jj = r - b16 * HID;
          sXh[buf ^ 1][s][nt * 16 + b16][jj] = (short)(pfu[k] >> 16);
          sXl[buf ^ 1][s][nt * 16 + b16][jj] = (short)(pfu[k] & 0xFFFFu);
        }
      } else {
        #pragma unroll
        for (int k = 0; k < NW; ++k) {
          int i = lane + 64 * k, s = i / WBH, r = i - s * WBH;
          int b16 = r / HID, jj = r - b16 * HID;
          short hi, lo; bf16split(pff[k], hi, lo);
          sXh[buf ^ 1][s][nt * 16 + b16][jj] = hi;
          sXl[buf ^ 1][s][nt * 16 + b16][jj] = lo;
        }
      }
    }
    staged = pf;

    // drain ring/act stores (and prefetch), then publish per-wave progress
    asm volatile("s_waitcnt vmcnt(0)" ::: "memory");
    __hip_atomic_store(fl, t0 + CH, __ATOMIC_RELAXED, __HIP_MEMORY_SCOPE_AGENT);
  }
}

__global__ __launch_bounds__(256) void linear_softmax(
    const float* __restrict__ act,    // [T][BATCH*HID]
    const float* __restrict__ w_lin,  // [NCLS][FEAT]
    const float* __restrict__ b_lin,
    float* __restrict__ out)          // [BATCH][NCLS]
{
  const int b   = blockIdx.x;
  const int tid = threadIdx.x;
  float accv[NCLS];
  #pragma unroll
  for (int c = 0; c < NCLS; ++c) accv[c] = 0.f;

  for (int i = tid; i < FEAT; i += 256) {
    int t = i / HID; int jj = i - t * HID;
    float a = act[(size_t)t * (BATCH * HID) + b * HID + jj];
    #pragma unroll
    for (int c = 0; c < NCLS; ++c)
      accv[c] += a * w_lin[(size_t)c * FEAT + i];
  }

  __shared__ float red[NCLS][256];
  #pragma unroll
  for (int c = 0; c < NCLS; ++c) red[c][tid] = accv[c];
  __syncthreads();
  for (int off = 128; off > 0; off >>= 1) {
    if (tid < off) {
      #pragma unroll
      for (int c = 0; c < NCLS; ++c) red[c][tid] += red[c][tid + off];
    }
    __syncthreads();
  }
  if (tid == 0) {
    float lg[NCLS]; float mx = -1e30f;
    #pragma unroll
    for (int c = 0; c < NCLS; ++c) { lg[c] = red[c][0] + b_lin[c]; mx = fmaxf(mx, lg[c]); }
    float sum = 0.f;
    #pragma unroll
    for (int c = 0; c < NCLS; ++c) { lg[c] = __expf(lg[c] - mx); sum += lg[c]; }
    float inv = 1.0f / sum;
    #pragma unroll
    for (int c = 0; c < NCLS; ++c) out[b * NCLS + c] = lg[c] * inv;
  }
}

extern "C" void kernel_launch(void* const* d_in, const int* in_sizes, int n_in,
                              void* d_out, int out_size, void* d_ws, size_t ws_size,
                              hipStream_t stream) {
  const float* xin  = (const float*)d_in[0];
  const float* wih  = (const float*)d_in[1];
  const float* whh  = (const float*)d_in[2];
  const float* bih  = (const float*)d_in[3];
  const float* bhh  = (const float*)d_in[4];
  const float* wlin = (const float*)d_in[5];
  const float* blin = (const float*)d_in[6];

  char*     ws    = (char*)d_ws;
  int*      flags = (int*)ws;
  uint32_t* ring  = (uint32_t*)(ws + FLAG_BYTES);
  float*    act   = (float*)(ws + FLAG_BYTES + RING_BYTES);

  lstm_pipeline<<<NPIPE * NLAYER, 256, 0, stream>>>(xin, wih, whh, bih, bhh, flags, ring, act);
  linear_softmax<<<BATCH, 256, 0, stream>>>(act, wlin, blin, (float*)d_out);
}

// Round 7
// 1997.616 us; speedup vs baseline: 5.7755x; 1.0666x over previous
//
#include <hip/hip_runtime.h>
#include <stdint.h>

#define T_SEQ  1132
#define BATCH  128
#define HID    13
#define G4     52
#define NLAYER 100
#define NPIPE  8            // pipelines, 16 batch each
#define LPW    4            // layers (waves) per WG
#define NWGP   25           // WGs per pipeline (NLAYER/LPW)
#define CH     4            // timesteps per chunk (1132 = 4*283)
#define RCL    4            // intra-WG LDS chunk slots (power of 2)
#define RC     8            // global ring chunk slots (power of 2)
#define RD     (RC*CH)
#define WBH    (16*HID)     // 208
#define CHUNK_U32 (CH*WBH)  // 832
#define NW     13           // u32 per lane per chunk (832/64)
#define NCLS   10
#define FEAT   (T_SEQ*HID)

#define FLAG_BYTES 65536
#define RING_U32_PER_WG ((size_t)RC * CHUNK_U32)
#define RING_BYTES ((size_t)(NPIPE*NWGP) * RING_U32_PER_WG * 4)

typedef float f32x4 __attribute__((ext_vector_type(4)));
typedef short s16x8 __attribute__((ext_vector_type(8)));

__device__ __forceinline__ float sigm(float x)  { return 1.0f / (1.0f + __expf(-x)); }
__device__ __forceinline__ float tanh_(float x) { return 1.0f - 2.0f / (1.0f + __expf(2.0f * x)); }

__device__ __forceinline__ void bf16split(float x, short& hi, short& lo) {
  union { float f; unsigned u; } a; a.f = x;
  unsigned hu = a.u & 0xFFFF0000u;
  hi = (short)(hu >> 16);
  union { float f; unsigned u; } h; h.u = hu;
  union { float f; unsigned u; } r; r.f = x - h.f;
  lo = (short)(r.u >> 16);
}

__device__ __forceinline__ int gspin_ge(int* p, int need) {
  int v = __hip_atomic_load(p, __ATOMIC_RELAXED, __HIP_MEMORY_SCOPE_AGENT);
  while (v < need) {
    __builtin_amdgcn_s_sleep(1);
    v = __hip_atomic_load(p, __ATOMIC_RELAXED, __HIP_MEMORY_SCOPE_AGENT);
  }
  return v;
}
__device__ __forceinline__ void lspin_ge(int* p, int need) {
  int v = __hip_atomic_load(p, __ATOMIC_ACQUIRE, __HIP_MEMORY_SCOPE_WORKGROUP);
  while (v < need) {
    __builtin_amdgcn_s_sleep(1);
    v = __hip_atomic_load(p, __ATOMIC_ACQUIRE, __HIP_MEMORY_SCOPE_WORKGROUP);
  }
}

// 8 pipelines x 16 batch. Each WG = 4 consecutive layers (1 per wave) of one
// pipeline. Intra-WG hops via LDS + LDS flags (no barriers after init);
// cross-WG hops (every 4th layer) via LLC ring + global flags (R5 scheme).
__global__ __launch_bounds__(256) void lstm_pipeline(
    const float* __restrict__ xin,   // [BATCH][T][HID]
    const float* __restrict__ w_ih,  // [L][G4][HID]
    const float* __restrict__ w_hh,  // [L][G4][HID]
    const float* __restrict__ b_ih,  // [L][G4]
    const float* __restrict__ b_hh,  // [L][G4]
    int*      flags,
    uint32_t* ring,
    float*    act)                   // [T][BATCH*HID]
{
  const int wg   = blockIdx.x;
  const int pp   = wg / NWGP;          // pipeline (batch group pp*16..+15)
  const int wgi  = wg - pp * NWGP;     // position along the layer chain
  const int tid  = threadIdx.x;
  const int lane = tid & 63;
  const int nt   = tid >> 6;           // wave = layer wgi*4+nt
  const int quad = lane >> 4;
  const int j    = lane & 15;
  const int l    = wgi * LPW + nt;
  const bool lastL = (l == NLAYER - 1);

  __shared__ __align__(16) short sXh[LPW][RCL][CH][16][16];  // staging (bf16 hi)
  __shared__ __align__(16) short sXl[LPW][RCL][CH][16][16];  // staging (bf16 lo)
  __shared__ __align__(16) short sHh[LPW][16][16];           // per-wave h state
  __shared__ __align__(16) short sHl[LPW][16][16];
  __shared__ __align__(16) uint32_t sOut[CHUNK_U32];         // wave3 flush bounce
  __shared__ int sProg[LPW];   // sProg[c]: timesteps ready for wave c (by wave c-1)
  __shared__ int sCons[LPW];   // sCons[c]: timesteps consumed by wave c

  int* flReadySelf = flags + ((pp * NWGP + wgi) * 2 + 0) * 16;
  int* flProgSelf  = flags + ((pp * NWGP + wgi) * 2 + 1) * 16;
  int* flReadyPrev = (wgi > 0)        ? flags + ((pp * NWGP + wgi - 1) * 2 + 0) * 16 : flags;
  int* flProgNext  = (wgi < NWGP - 1) ? flags + ((pp * NWGP + wgi + 1) * 2 + 1) * 16 : flags;

  if (lane == 0) {
    if (nt == 3 && wgi < NWGP - 1)
      __hip_atomic_store(flReadySelf, 0, __ATOMIC_RELAXED, __HIP_MEMORY_SCOPE_AGENT);
    if (nt == 0 && wgi > 0)
      __hip_atomic_store(flProgSelf, 0, __ATOMIC_RELAXED, __HIP_MEMORY_SCOPE_AGENT);
  }

  // zero LDS (pads j,k >= 13 must stay 0 forever; h0 = 0)
  for (int i = tid; i < LPW * RCL * CH * 256; i += 256) { ((short*)sXh)[i] = 0; ((short*)sXl)[i] = 0; }
  for (int i = tid; i < LPW * 256; i += 256) { ((short*)sHh)[i] = 0; ((short*)sHl)[i] = 0; }
  if (tid < LPW) { sProg[tid] = 0; sCons[tid] = 0; }
  __syncthreads();   // the only barrier; waves free-run after this

  // static B-fragments (gate' = 16q+j <-> original gate q*13+j), hi/lo + bias
  s16x8 Bh[4], Bl[4];
  float bq[4];
  #pragma unroll
  for (int q = 0; q < 4; ++q) {
    #pragma unroll
    for (int jj = 0; jj < 8; ++jj) {
      int k = quad * 8 + jj;
      float w = 0.f;
      if (j < HID) {
        int g = q * HID + j;
        if (k < HID)                      w = w_ih[(size_t)(l * G4 + g) * HID + k];
        else if (k >= 16 && k < 16 + HID) w = w_hh[(size_t)(l * G4 + g) * HID + (k - 16)];
      }
      short hi, lo; bf16split(w, hi, lo);
      Bh[q][jj] = hi; Bl[q][jj] = lo;
    }
    bq[q] = (j < HID) ? (b_ih[l * G4 + q * HID + j] + b_hh[l * G4 + q * HID + j]) : 0.f;
  }

  // loop-invariant unpack maps for lane-linear chunk index i = lane + 64k
  int off0[NW];   // element offset within one [CH][16][16] slot
  int xoff[NW];   // xin gather offset (wave0/wgi0)
  int aoff[NW];   // act scatter offset (wave3/last)
  #pragma unroll
  for (int k = 0; k < NW; ++k) {
    int i = lane + 64 * k;
    int s = i / WBH, r = i - s * WBH;
    int b16 = r / HID, jj = r - b16 * HID;
    off0[k] = s * 256 + b16 * 16 + jj;
    xoff[k] = b16 * (T_SEQ * HID) + s * HID + jj;
    aoff[k] = s * (BATCH * HID) + pp * WBH + r;
  }

  float cstate[4] = {0.f, 0.f, 0.f, 0.f};
  int cp = 0, cn = 0;
  bool staged = false;
  uint32_t pfu[NW];
  float    pff[NW];

  const uint32_t* ringprev = ring + (size_t)(pp * NWGP + wgi - 1) * RING_U32_PER_WG;
  uint32_t*       ringmine = ring + (size_t)(pp * NWGP + wgi)     * RING_U32_PER_WG;
  const size_t    xbase    = (size_t)(pp * 16) * (T_SEQ * HID);
  short* myXh = &sXh[nt][0][0][0][0];
  short* myXl = &sXl[nt][0][0][0][0];

  #pragma unroll 1
  for (int t0 = 0; t0 < T_SEQ; t0 += CH) {
    const int ci  = t0 >> 2;
    const int buf = ci & (RCL - 1);
    bool pf = false;

    // ---- acquire input chunk ----
    if (nt == 0) {
      if (!staged) {
        if (wgi > 0) {
          if (cp < t0 + CH) cp = gspin_ge(flReadyPrev, t0 + CH);
          const uint32_t* src = ringprev + (size_t)(ci & (RC - 1)) * CHUNK_U32;
          #pragma unroll
          for (int k = 0; k < NW; ++k)
            pfu[k] = __hip_atomic_load(&src[lane + 64 * k], __ATOMIC_RELAXED, __HIP_MEMORY_SCOPE_AGENT);
          #pragma unroll
          for (int k = 0; k < NW; ++k) {
            myXh[buf * 1024 + off0[k]] = (short)(pfu[k] >> 16);
            myXl[buf * 1024 + off0[k]] = (short)(pfu[k] & 0xFFFFu);
          }
          asm volatile("s_waitcnt vmcnt(0)" ::: "memory");
          if (lane == 0)
            __hip_atomic_store(flProgSelf, t0 + CH, __ATOMIC_RELAXED, __HIP_MEMORY_SCOPE_AGENT);
        } else {
          #pragma unroll
          for (int k = 0; k < NW; ++k)
            pff[k] = xin[xbase + xoff[k] + (size_t)t0 * HID];
          #pragma unroll
          for (int k = 0; k < NW; ++k) {
            short hi, lo; bf16split(pff[k], hi, lo);
            myXh[buf * 1024 + off0[k]] = hi;
            myXl[buf * 1024 + off0[k]] = lo;
          }
        }
      }
      // prefetch chunk ci+1 into registers (hidden under compute)
      if (t0 + CH < T_SEQ) {
        if (wgi > 0) {
          if (cp < t0 + 2 * CH)
            cp = __hip_atomic_load(flReadyPrev, __ATOMIC_RELAXED, __HIP_MEMORY_SCOPE_AGENT);
          if (cp >= t0 + 2 * CH) {
            const uint32_t* src = ringprev + (size_t)((ci + 1) & (RC - 1)) * CHUNK_U32;
            #pragma unroll
            for (int k = 0; k < NW; ++k)
              pfu[k] = __hip_atomic_load(&src[lane + 64 * k], __ATOMIC_RELAXED, __HIP_MEMORY_SCOPE_AGENT);
            pf = true;
          }
        } else {
          #pragma unroll
          for (int k = 0; k < NW; ++k)
            pff[k] = xin[xbase + xoff[k] + (size_t)(t0 + CH) * HID];
          pf = true;
        }
      }
    } else {
      lspin_ge(&sProg[nt], t0 + CH);
    }

    // ---- backpressure for output target ----
    if (nt < 3) {
      int need = t0 + CH - RCL * CH;
      if (need > 0) lspin_ge(&sCons[nt + 1], need);
    } else if (!lastL) {
      int need = t0 + CH - RD;
      if (need > 0 && cn < need) cn = gspin_ge(flProgNext, need);
    }

    // ---- compute CH steps (wave-private) ----
    #pragma unroll
    for (int s = 0; s < CH; ++s) {
      const short* ph = (quad < 2) ? &myXh[buf * 1024 + s * 256 + j * 16 + quad * 8]
                                   : &sHh[nt][j][(quad - 2) * 8];
      const short* pl = (quad < 2) ? &myXl[buf * 1024 + s * 256 + j * 16 + quad * 8]
                                   : &sHl[nt][j][(quad - 2) * 8];
      s16x8 Azh = *(const s16x8*)ph;
      s16x8 Azl = *(const s16x8*)pl;

      f32x4 acc[4];
      #pragma unroll
      for (int q = 0; q < 4; ++q) {
        f32x4 a = { bq[q], bq[q], bq[q], bq[q] };
        a = __builtin_amdgcn_mfma_f32_16x16x32_bf16(Azh, Bh[q], a, 0, 0, 0);
        a = __builtin_amdgcn_mfma_f32_16x16x32_bf16(Azh, Bl[q], a, 0, 0, 0);
        a = __builtin_amdgcn_mfma_f32_16x16x32_bf16(Azl, Bh[q], a, 0, 0, 0);
        acc[q] = a;
      }

      if (j < HID) {
        #pragma unroll
        for (int r = 0; r < 4; ++r) {
          float gi = acc[0][r], gf = acc[1][r], gg = acc[2][r], go = acc[3][r];
          float cn_ = sigm(gf) * cstate[r] + sigm(gi) * tanh_(gg);
          cstate[r] = cn_;
          float hn = sigm(go) * tanh_(cn_);
          short hi, lo; bf16split(hn, hi, lo);
          int br = quad * 4 + r;
          sHh[nt][br][j] = hi;
          sHl[nt][br][j] = lo;
          if (nt < 3) {
            sXh[nt + 1][buf][s][br][j] = hi;   // produce directly into consumer
            sXl[nt + 1][buf][s][br][j] = lo;
          } else {
            sOut[s * WBH + br * HID + j] =
                lastL ? __float_as_uint(hn)
                      : (((uint32_t)(uint16_t)hi << 16) | (uint32_t)(uint16_t)lo);
          }
        }
      }
    }

    // ---- publish output ----
    if (nt < 3) {
      if (lane == 0)
        __hip_atomic_store(&sProg[nt + 1], t0 + CH, __ATOMIC_RELEASE, __HIP_MEMORY_SCOPE_WORKGROUP);
    } else if (!lastL) {
      uint32_t* dst = ringmine + (size_t)(ci & (RC - 1)) * CHUNK_U32;
      #pragma unroll
      for (int k = 0; k < NW; ++k)
        __hip_atomic_store(&dst[lane + 64 * k], sOut[lane + 64 * k],
                           __ATOMIC_RELAXED, __HIP_MEMORY_SCOPE_AGENT);
      asm volatile("s_waitcnt vmcnt(0)" ::: "memory");
      if (lane == 0)
        __hip_atomic_store(flReadySelf, t0 + CH, __ATOMIC_RELAXED, __HIP_MEMORY_SCOPE_AGENT);
    } else {
      #pragma unroll
      for (int k = 0; k < NW; ++k)
        act[(size_t)t0 * (BATCH * HID) + aoff[k]] = __uint_as_float(sOut[lane + 64 * k]);
    }
    // mark my input chunk consumed (slot reusable by my producer)
    if (nt > 0 && lane == 0)
      __hip_atomic_store(&sCons[nt], t0 + CH, __ATOMIC_RELEASE, __HIP_MEMORY_SCOPE_WORKGROUP);

    // ---- wave0: restage prefetched chunk, free ring slot early ----
    if (nt == 0) {
      if (pf) {
        int nbuf = (ci + 1) & (RCL - 1);
        if (wgi > 0) {
          #pragma unroll
          for (int k = 0; k < NW; ++k) {
            myXh[nbuf * 1024 + off0[k]] = (short)(pfu[k] >> 16);
            myXl[nbuf * 1024 + off0[k]] = (short)(pfu[k] & 0xFFFFu);
          }
          asm volatile("s_waitcnt vmcnt(0)" ::: "memory");
          if (lane == 0)
            __hip_atomic_store(flProgSelf, t0 + 2 * CH, __ATOMIC_RELAXED, __HIP_MEMORY_SCOPE_AGENT);
        } else {
          #pragma unroll
          for (int k = 0; k < NW; ++k) {
            short hi, lo; bf16split(pff[k], hi, lo);
            myXh[nbuf * 1024 + off0[k]] = hi;
            myXl[nbuf * 1024 + off0[k]] = lo;
          }
        }
      }
      staged = pf;
    }
  }
}

__global__ __launch_bounds__(256) void linear_softmax(
    const float* __restrict__ act,    // [T][BATCH*HID]
    const float* __restrict__ w_lin,  // [NCLS][FEAT]
    const float* __restrict__ b_lin,
    float* __restrict__ out)          // [BATCH][NCLS]
{
  const int b   = blockIdx.x;
  const int tid = threadIdx.x;
  float accv[NCLS];
  #pragma unroll
  for (int c = 0; c < NCLS; ++c) accv[c] = 0.f;

  for (int i = tid; i < FEAT; i += 256) {
    int t = i / HID; int jj = i - t * HID;
    float a = act[(size_t)t * (BATCH * HID) + b * HID + jj];
    #pragma unroll
    for (int c = 0; c < NCLS; ++c)
      accv[c] += a * w_lin[(size_t)c * FEAT + i];
  }

  __shared__ float red[NCLS][256];
  #pragma unroll
  for (int c = 0; c < NCLS; ++c) red[c][tid] = accv[c];
  __syncthreads();
  for (int off = 128; off > 0; off >>= 1) {
    if (tid < off) {
      #pragma unroll
      for (int c = 0; c < NCLS; ++c) red[c][tid] += red[c][tid + off];
    }
    __syncthreads();
  }
  if (tid == 0) {
    float lg[NCLS]; float mx = -1e30f;
    #pragma unroll
    for (int c = 0; c < NCLS; ++c) { lg[c] = red[c][0] + b_lin[c]; mx = fmaxf(mx, lg[c]); }
    float sum = 0.f;
    #pragma unroll
    for (int c = 0; c < NCLS; ++c) { lg[c] = __expf(lg[c] - mx); sum += lg[c]; }
    float inv = 1.0f / sum;
    #pragma unroll
    for (int c = 0; c < NCLS; ++c) out[b * NCLS + c] = lg[c] * inv;
  }
}

extern "C" void kernel_launch(void* const* d_in, const int* in_sizes, int n_in,
                              void* d_out, int out_size, void* d_ws, size_t ws_size,
                              hipStream_t stream) {
  const float* xin  = (const float*)d_in[0];
  const float* wih  = (const float*)d_in[1];
  const float* whh  = (const float*)d_in[2];
  const float* bih  = (const float*)d_in[3];
  const float* bhh  = (const float*)d_in[4];
  const float* wlin = (const float*)d_in[5];
  const float* blin = (const float*)d_in[6];

  char*     ws    = (char*)d_ws;
  int*      flags = (int*)ws;
  uint32_t* ring  = (uint32_t*)(ws + FLAG_BYTES);
  float*    act   = (float*)(ws + FLAG_BYTES + RING_BYTES);

  lstm_pipeline<<<NPIPE * NWGP, 256, 0, stream>>>(xin, wih, whh, bih, bhh, flags, ring, act);
  linear_softmax<<<BATCH, 256, 0, stream>>>(act, wlin, blin, (float*)d_out);
}

// Round 8
// 1742.676 us; speedup vs baseline: 6.6204x; 1.1463x over previous
//
#include <hip/hip_runtime.h>
#include <stdint.h>

#define T_SEQ  1132
#define BATCH  128
#define HID    13
#define G4     52
#define NLAYER 100
#define NPIPE  8            // pipelines, 16 batch each
#define LPW    4            // compute waves (layers) per WG
#define NWGP   25           // WGs per pipeline
#define CH     4            // timesteps per chunk (1132 = 4*283)
#define RCL    4            // intra-WG LDS chunk slots (power of 2)
#define RC     8            // global ring chunk slots (power of 2)
#define RD     (RC*CH)
#define WBH    (16*HID)     // 208
#define PLANE  1024         // shorts per plane = CH*16*16
#define CHUNK_U32 1024      // ring u32 per chunk: hi-plane 512 | lo-plane 512
#define NCLS   10
#define FEAT   (T_SEQ*HID)

#define FLAG_BYTES 65536
#define RING_U32_PER_WG ((size_t)RC * CHUNK_U32)
#define RING_BYTES ((size_t)(NPIPE*NWGP) * RING_U32_PER_WG * 4)

typedef float f32x4 __attribute__((ext_vector_type(4)));
typedef short s16x8 __attribute__((ext_vector_type(8)));

__device__ __forceinline__ float sigm(float x)  { return 1.0f / (1.0f + __expf(-x)); }
__device__ __forceinline__ float tanh_(float x) { return 1.0f - 2.0f / (1.0f + __expf(2.0f * x)); }

__device__ __forceinline__ void bf16split(float x, short& hi, short& lo) {
  union { float f; unsigned u; } a; a.f = x;
  unsigned hu = a.u & 0xFFFF0000u;
  hi = (short)(hu >> 16);
  union { float f; unsigned u; } h; h.u = hu;
  union { float f; unsigned u; } r; r.f = x - h.f;
  lo = (short)(r.u >> 16);
}

__device__ __forceinline__ void lspin_ge(int* p, int need) {
  int v = __hip_atomic_load(p, __ATOMIC_ACQUIRE, __HIP_MEMORY_SCOPE_WORKGROUP);
  while (v < need) {
    __builtin_amdgcn_s_sleep(1);
    v = __hip_atomic_load(p, __ATOMIC_ACQUIRE, __HIP_MEMORY_SCOPE_WORKGROUP);
  }
}

// 8 pipelines x 16 batch. Each WG = 4 consecutive layers (waves 0-3) + 1 DMA
// wave (wave 4) that owns ALL global traffic with decoupled in/out counters.
// Compute handshakes are pure LDS; cross-WG hops via LLC ring, fully hidden
// behind the DMA wave's slack (RCL=4 chunks in, RCL=4 chunks out).
__global__ __launch_bounds__(320) void lstm_pipeline(
    const float* __restrict__ xin,   // [BATCH][T][HID]
    const float* __restrict__ w_ih,  // [L][G4][HID]
    const float* __restrict__ w_hh,  // [L][G4][HID]
    const float* __restrict__ b_ih,  // [L][G4]
    const float* __restrict__ b_hh,  // [L][G4]
    int*      flags,
    uint32_t* ring,
    float*    act)                   // [T][BATCH*HID]
{
  const int wg   = blockIdx.x;
  const int pp   = wg / NWGP;          // pipeline (batch group pp*16..+15)
  const int wgi  = wg - pp * NWGP;     // chain position
  const int tid  = threadIdx.x;
  const int lane = tid & 63;
  const int nt   = tid >> 6;           // 0..3 compute, 4 DMA
  const int quad = lane >> 4;
  const int j    = lane & 15;
  const bool lastWG = (wgi == NWGP - 1);

  __shared__ __align__(16) short sXP[LPW][RCL][2][PLANE]; // staging, [hi|lo] planes
  __shared__ __align__(16) short sHh[LPW][16][16];        // per-wave h state
  __shared__ __align__(16) short sHl[LPW][16][16];
  __shared__ __align__(16) uint32_t sOutR[RCL][CHUNK_U32]; // wave3 -> DMA LDS ring
  __shared__ int sProg[LPW];   // input chunks ready for wave c
  __shared__ int sCons[LPW];   // input chunks consumed by wave c
  __shared__ int sProgOut;     // chunks wave3 produced into sOutR
  __shared__ int sConsOut;     // chunks DMA flushed out of sOutR

  int* flReadySelf = flags + ((pp * NWGP + wgi) * 2 + 0) * 16;
  int* flProgSelf  = flags + ((pp * NWGP + wgi) * 2 + 1) * 16;
  int* flReadyPrev = (wgi > 0) ? flags + ((pp * NWGP + wgi - 1) * 2 + 0) * 16 : flags;
  int* flProgNext  = (!lastWG) ? flags + ((pp * NWGP + wgi + 1) * 2 + 1) * 16 : flags;

  if (nt == LPW && lane == 0) {
    __hip_atomic_store(flReadySelf, 0, __ATOMIC_RELAXED, __HIP_MEMORY_SCOPE_AGENT);
    __hip_atomic_store(flProgSelf,  0, __ATOMIC_RELAXED, __HIP_MEMORY_SCOPE_AGENT);
  }

  // zero LDS (pads j,k >= 13 must stay 0 forever; h0 = 0)
  for (int i = tid; i < LPW * RCL * 2 * PLANE; i += 320) ((short*)sXP)[i] = 0;
  for (int i = tid; i < LPW * 256; i += 320) { ((short*)sHh)[i] = 0; ((short*)sHl)[i] = 0; }
  for (int i = tid; i < RCL * CHUNK_U32; i += 320) ((uint32_t*)sOutR)[i] = 0;
  if (tid < LPW) { sProg[tid] = 0; sCons[tid] = 0; }
  if (tid == 0) { sProgOut = 0; sConsOut = 0; }
  __syncthreads();   // the only barrier

  if (nt < LPW) {
    // ================= compute wave: layer l =================
    const int l = wgi * LPW + nt;
    const bool lastL = (l == NLAYER - 1);

    // static B-fragments (gate' = 16q+j <-> original gate q*13+j), hi/lo + bias
    s16x8 Bh[4], Bl[4];
    float bq[4];
    #pragma unroll
    for (int q = 0; q < 4; ++q) {
      #pragma unroll
      for (int jj = 0; jj < 8; ++jj) {
        int k = quad * 8 + jj;
        float w = 0.f;
        if (j < HID) {
          int g = q * HID + j;
          if (k < HID)                      w = w_ih[(size_t)(l * G4 + g) * HID + k];
          else if (k >= 16 && k < 16 + HID) w = w_hh[(size_t)(l * G4 + g) * HID + (k - 16)];
        }
        short hi, lo; bf16split(w, hi, lo);
        Bh[q][jj] = hi; Bl[q][jj] = lo;
      }
      bq[q] = (j < HID) ? (b_ih[l * G4 + q * HID + j] + b_hh[l * G4 + q * HID + j]) : 0.f;
    }

    float cstate[4] = {0.f, 0.f, 0.f, 0.f};

    #pragma unroll 1
    for (int t0 = 0; t0 < T_SEQ; t0 += CH) {
      const int slot = (t0 >> 2) & (RCL - 1);

      lspin_ge(&sProg[nt], t0 + CH);                 // input ready
      {                                              // output slot free
        int need = t0 + CH - RCL * CH;
        if (need > 0) {
          if (nt < 3) lspin_ge(&sCons[nt + 1], need);
          else        lspin_ge(&sConsOut,      need);
        }
      }

      const short* xh = &sXP[nt][slot][0][0];
      const short* xl = &sXP[nt][slot][1][0];

      #pragma unroll
      for (int s = 0; s < CH; ++s) {
        const short* ph = (quad < 2) ? &xh[s * 256 + j * 16 + quad * 8] : &sHh[nt][j][(quad - 2) * 8];
        const short* pl = (quad < 2) ? &xl[s * 256 + j * 16 + quad * 8] : &sHl[nt][j][(quad - 2) * 8];
        s16x8 Azh = *(const s16x8*)ph;
        s16x8 Azl = *(const s16x8*)pl;

        f32x4 acc[4];
        #pragma unroll
        for (int q = 0; q < 4; ++q) {
          f32x4 a = { bq[q], bq[q], bq[q], bq[q] };
          a = __builtin_amdgcn_mfma_f32_16x16x32_bf16(Azh, Bh[q], a, 0, 0, 0);
          a = __builtin_amdgcn_mfma_f32_16x16x32_bf16(Azh, Bl[q], a, 0, 0, 0);
          a = __builtin_amdgcn_mfma_f32_16x16x32_bf16(Azl, Bh[q], a, 0, 0, 0);
          acc[q] = a;
        }

        if (j < HID) {
          #pragma unroll
          for (int r = 0; r < 4; ++r) {
            float gi = acc[0][r], gf = acc[1][r], gg = acc[2][r], go = acc[3][r];
            float cn_ = sigm(gf) * cstate[r] + sigm(gi) * tanh_(gg);
            cstate[r] = cn_;
            float hn = sigm(go) * tanh_(cn_);
            short hi, lo; bf16split(hn, hi, lo);
            int br = quad * 4 + r;
            sHh[nt][br][j] = hi;
            sHl[nt][br][j] = lo;
            if (nt < 3) {
              sXP[nt + 1][slot][0][s * 256 + br * 16 + j] = hi;
              sXP[nt + 1][slot][1][s * 256 + br * 16 + j] = lo;
            } else if (!lastL) {
              short* so = (short*)&sOutR[slot][0];
              so[s * 256 + br * 16 + j]        = hi;   // hi-plane
              so[1024 + s * 256 + br * 16 + j] = lo;   // lo-plane
            } else {
              sOutR[slot][s * WBH + br * HID + j] = __float_as_uint(hn);
            }
          }
        }
      }

      if (lane == 0) {
        __hip_atomic_store(&sCons[nt], t0 + CH, __ATOMIC_RELEASE, __HIP_MEMORY_SCOPE_WORKGROUP);
        if (nt < 3)
          __hip_atomic_store(&sProg[nt + 1], t0 + CH, __ATOMIC_RELEASE, __HIP_MEMORY_SCOPE_WORKGROUP);
        else
          __hip_atomic_store(&sProgOut, t0 + CH, __ATOMIC_RELEASE, __HIP_MEMORY_SCOPE_WORKGROUP);
      }
    }
  } else {
    // ================= DMA wave: decoupled in/out =================
    const uint32_t* ringprev = ring + (size_t)(pp * NWGP + wgi - 1) * RING_U32_PER_WG;
    uint32_t*       ringmine = ring + (size_t)(pp * NWGP + wgi)     * RING_U32_PER_WG;
    const size_t    xbase    = (size_t)(pp * 16) * (T_SEQ * HID);

    int off0[13], xoff[13], aoff[13];
    #pragma unroll
    for (int k = 0; k < 13; ++k) {
      int i = lane + 64 * k;
      int s = i / WBH, r = i - s * WBH;
      int b16 = r / HID, jj = r - b16 * HID;
      off0[k] = s * 256 + b16 * 16 + jj;
      xoff[k] = b16 * (T_SEQ * HID) + s * HID + jj;
      aoff[k] = s * (BATCH * HID) + pp * WBH + r;
    }

    int t_in = 0, t_out = 0;
    int cPrev = 0, cNext = 0;

    while (t_in < T_SEQ || t_out < T_SEQ) {
      bool prog = false;

      // ---- input side: stage next chunk for wave0 (up to RCL ahead) ----
      if (t_in < T_SEQ) {
        bool ok = true;
        int need = t_in + CH - RCL * CH;
        if (need > 0 &&
            __hip_atomic_load(&sCons[0], __ATOMIC_ACQUIRE, __HIP_MEMORY_SCOPE_WORKGROUP) < need)
          ok = false;
        if (ok && wgi > 0 && cPrev < t_in + CH) {
          cPrev = __hip_atomic_load(flReadyPrev, __ATOMIC_RELAXED, __HIP_MEMORY_SCOPE_AGENT);
          if (cPrev < t_in + CH) ok = false;
        }
        if (ok) {
          const int slot = (t_in >> 2) & (RCL - 1);
          if (wgi > 0) {
            const uint32_t* src = ringprev + (size_t)((t_in >> 2) & (RC - 1)) * CHUNK_U32;
            uint32_t v[16];
            #pragma unroll
            for (int k = 0; k < 16; ++k)
              v[k] = __hip_atomic_load(&src[lane + 64 * k], __ATOMIC_RELAXED, __HIP_MEMORY_SCOPE_AGENT);
            uint32_t* dst = (uint32_t*)&sXP[0][slot][0][0];
            #pragma unroll
            for (int k = 0; k < 16; ++k) dst[lane + 64 * k] = v[k];
            asm volatile("s_waitcnt vmcnt(0)" ::: "memory");   // loads done -> slot consumed
            if (lane == 0)
              __hip_atomic_store(flProgSelf, t_in + CH, __ATOMIC_RELAXED, __HIP_MEMORY_SCOPE_AGENT);
          } else {
            float v[13];
            #pragma unroll
            for (int k = 0; k < 13; ++k)
              v[k] = xin[xbase + xoff[k] + (size_t)t_in * HID];
            #pragma unroll
            for (int k = 0; k < 13; ++k) {
              short hi, lo; bf16split(v[k], hi, lo);
              sXP[0][slot][0][off0[k]] = hi;
              sXP[0][slot][1][off0[k]] = lo;
            }
          }
          if (lane == 0)
            __hip_atomic_store(&sProg[0], t_in + CH, __ATOMIC_RELEASE, __HIP_MEMORY_SCOPE_WORKGROUP);
          t_in += CH; prog = true;
        }
      }

      // ---- output side: flush wave3's chunks ----
      if (t_out < T_SEQ) {
        bool ok = (__hip_atomic_load(&sProgOut, __ATOMIC_ACQUIRE, __HIP_MEMORY_SCOPE_WORKGROUP) >= t_out + CH);
        if (ok && !lastWG) {
          int need = t_out + CH - RD;
          if (need > 0 && cNext < need) {
            cNext = __hip_atomic_load(flProgNext, __ATOMIC_RELAXED, __HIP_MEMORY_SCOPE_AGENT);
            if (cNext < need) ok = false;
          }
        }
        if (ok) {
          const int slot = (t_out >> 2) & (RCL - 1);
          if (!lastWG) {
            uint32_t* dst = ringmine + (size_t)((t_out >> 2) & (RC - 1)) * CHUNK_U32;
            #pragma unroll
            for (int k = 0; k < 16; ++k)
              __hip_atomic_store(&dst[lane + 64 * k], sOutR[slot][lane + 64 * k],
                                 __ATOMIC_RELAXED, __HIP_MEMORY_SCOPE_AGENT);
            asm volatile("s_waitcnt vmcnt(0)" ::: "memory");
            if (lane == 0)
              __hip_atomic_store(flReadySelf, t_out + CH, __ATOMIC_RELAXED, __HIP_MEMORY_SCOPE_AGENT);
          } else {
            #pragma unroll
            for (int k = 0; k < 13; ++k)
              act[(size_t)t_out * (BATCH * HID) + aoff[k]] =
                  __uint_as_float(sOutR[slot][lane + 64 * k]);
            asm volatile("s_waitcnt vmcnt(0)" ::: "memory");
          }
          if (lane == 0)
            __hip_atomic_store(&sConsOut, t_out + CH, __ATOMIC_RELEASE, __HIP_MEMORY_SCOPE_WORKGROUP);
          t_out += CH; prog = true;
        }
      }

      if (!prog) __builtin_amdgcn_s_sleep(1);
    }
  }
}

__global__ __launch_bounds__(256) void linear_softmax(
    const float* __restrict__ act,    // [T][BATCH*HID]
    const float* __restrict__ w_lin,  // [NCLS][FEAT]
    const float* __restrict__ b_lin,
    float* __restrict__ out)          // [BATCH][NCLS]
{
  const int b   = blockIdx.x;
  const int tid = threadIdx.x;
  float accv[NCLS];
  #pragma unroll
  for (int c = 0; c < NCLS; ++c) accv[c] = 0.f;

  for (int i = tid; i < FEAT; i += 256) {
    int t = i / HID; int jj = i - t * HID;
    float a = act[(size_t)t * (BATCH * HID) + b * HID + jj];
    #pragma unroll
    for (int c = 0; c < NCLS; ++c)
      accv[c] += a * w_lin[(size_t)c * FEAT + i];
  }

  __shared__ float red[NCLS][256];
  #pragma unroll
  for (int c = 0; c < NCLS; ++c) red[c][tid] = accv[c];
  __syncthreads();
  for (int off = 128; off > 0; off >>= 1) {
    if (tid < off) {
      #pragma unroll
      for (int c = 0; c < NCLS; ++c) red[c][tid] += red[c][tid + off];
    }
    __syncthreads();
  }
  if (tid == 0) {
    float lg[NCLS]; float mx = -1e30f;
    #pragma unroll
    for (int c = 0; c < NCLS; ++c) { lg[c] = red[c][0] + b_lin[c]; mx = fmaxf(mx, lg[c]); }
    float sum = 0.f;
    #pragma unroll
    for (int c = 0; c < NCLS; ++c) { lg[c] = __expf(lg[c] - mx); sum += lg[c]; }
    float inv = 1.0f / sum;
    #pragma unroll
    for (int c = 0; c < NCLS; ++c) out[b * NCLS + c] = lg[c] * inv;
  }
}

extern "C" void kernel_launch(void* const* d_in, const int* in_sizes, int n_in,
                              void* d_out, int out_size, void* d_ws, size_t ws_size,
                              hipStream_t stream) {
  const float* xin  = (const float*)d_in[0];
  const float* wih  = (const float*)d_in[1];
  const float* whh  = (const float*)d_in[2];
  const float* bih  = (const float*)d_in[3];
  const float* bhh  = (const float*)d_in[4];
  const float* wlin = (const float*)d_in[5];
  const float* blin = (const float*)d_in[6];

  char*     ws    = (char*)d_ws;
  int*      flags = (int*)ws;
  uint32_t* ring  = (uint32_t*)(ws + FLAG_BYTES);
  float*    act   = (float*)(ws + FLAG_BYTES + RING_BYTES);

  lstm_pipeline<<<NPIPE * NWGP, 320, 0, stream>>>(xin, wih, whh, bih, bhh, flags, ring, act);
  linear_softmax<<<BATCH, 256, 0, stream>>>(act, wlin, blin, (float*)d_out);
}

// Round 9
// 1548.221 us; speedup vs baseline: 7.4519x; 1.1256x over previous
//
#include <hip/hip_runtime.h>
#include <stdint.h>

#define T_SEQ  1132
#define BATCH  128
#define HID    13
#define G4     52
#define NLAYER 100
#define NPIPE  8            // pipelines, 16 batch each
#define LPW    4            // compute waves (layers) per WG
#define NWGP   25           // WGs per pipeline
#define CH     8            // timesteps per chunk (1132 = 8*141 + 4)
#define NCH    142          // ceil(T_SEQ/CH)
#define RCL    2            // intra-WG LDS chunk slots (power of 2)
#define RC     4            // global ring chunk slots (power of 2)
#define WBH    (16*HID)     // 208
#define PLANE  (CH*256)     // 2048 shorts per plane
#define CHUNK_U32 2048      // ring u32 per chunk: hi-plane 1024 | lo-plane 1024
#define NCLS   10
#define FEAT   (T_SEQ*HID)

#define FLAG_BYTES 65536
#define RING_U32_PER_WG ((size_t)RC * CHUNK_U32)
#define RING_BYTES ((size_t)(NPIPE*NWGP) * RING_U32_PER_WG * 4)

typedef float f32x4 __attribute__((ext_vector_type(4)));
typedef short s16x8 __attribute__((ext_vector_type(8)));

__device__ __forceinline__ float sigm(float x) {
  return __builtin_amdgcn_rcpf(1.0f + __expf(-x));
}
__device__ __forceinline__ float tanh_(float x) {
  return 1.0f - 2.0f * __builtin_amdgcn_rcpf(1.0f + __expf(2.0f * x));
}

__device__ __forceinline__ void bf16split(float x, short& hi, short& lo) {
  union { float f; unsigned u; } a; a.f = x;
  unsigned hu = a.u & 0xFFFF0000u;
  hi = (short)(hu >> 16);
  union { float f; unsigned u; } h; h.u = hu;
  union { float f; unsigned u; } r; r.f = x - h.f;
  lo = (short)(r.u >> 16);
}

__device__ __forceinline__ void lspin_ge(int* p, int need) {
  int v = __hip_atomic_load(p, __ATOMIC_ACQUIRE, __HIP_MEMORY_SCOPE_WORKGROUP);
  while (v < need) {
    __builtin_amdgcn_s_sleep(1);
    v = __hip_atomic_load(p, __ATOMIC_ACQUIRE, __HIP_MEMORY_SCOPE_WORKGROUP);
  }
}

// 8 pipelines x 16 batch; WG = 4 consecutive layers (waves 0-3) + 1 DMA wave.
// All flags count CHUNKS. Chunk = 8 timesteps (last chunk = 4).
__global__ __launch_bounds__(320) void lstm_pipeline(
    const float* __restrict__ xin,   // [BATCH][T][HID]
    const float* __restrict__ w_ih,  // [L][G4][HID]
    const float* __restrict__ w_hh,  // [L][G4][HID]
    const float* __restrict__ b_ih,  // [L][G4]
    const float* __restrict__ b_hh,  // [L][G4]
    int*      flags,
    uint32_t* ring,
    float*    act)                   // [T][BATCH*HID]
{
  const int wg   = blockIdx.x;
  const int pp   = wg / NWGP;
  const int wgi  = wg - pp * NWGP;
  const int tid  = threadIdx.x;
  const int lane = tid & 63;
  const int nt   = tid >> 6;           // 0..3 compute, 4 DMA
  const int quad = lane >> 4;
  const int j    = lane & 15;
  const bool lastWG = (wgi == NWGP - 1);

  __shared__ __align__(16) short sXP[LPW][RCL][2][PLANE];  // staging [hi|lo]
  __shared__ __align__(16) short sHh[LPW][16][16];
  __shared__ __align__(16) short sHl[LPW][16][16];
  __shared__ __align__(16) uint32_t sOutR[RCL][CHUNK_U32]; // wave3 -> DMA
  __shared__ int sProg[LPW];   // chunks staged for wave c
  __shared__ int sCons[LPW];   // chunks consumed by wave c
  __shared__ int sProgOut;     // chunks wave3 wrote to sOutR
  __shared__ int sConsOut;     // chunks DMA flushed

  int* flReadySelf = flags + ((pp * NWGP + wgi) * 2 + 0) * 16;
  int* flProgSelf  = flags + ((pp * NWGP + wgi) * 2 + 1) * 16;
  int* flReadyPrev = (wgi > 0) ? flags + ((pp * NWGP + wgi - 1) * 2 + 0) * 16 : flags;
  int* flProgNext  = (!lastWG) ? flags + ((pp * NWGP + wgi + 1) * 2 + 1) * 16 : flags;

  if (nt == LPW && lane == 0) {
    __hip_atomic_store(flReadySelf, 0, __ATOMIC_RELAXED, __HIP_MEMORY_SCOPE_AGENT);
    __hip_atomic_store(flProgSelf,  0, __ATOMIC_RELAXED, __HIP_MEMORY_SCOPE_AGENT);
  }

  for (int i = tid; i < LPW * RCL * 2 * PLANE; i += 320) ((short*)sXP)[i] = 0;
  for (int i = tid; i < LPW * 256; i += 320) { ((short*)sHh)[i] = 0; ((short*)sHl)[i] = 0; }
  for (int i = tid; i < RCL * CHUNK_U32; i += 320) ((uint32_t*)sOutR)[i] = 0;
  if (tid < LPW) { sProg[tid] = 0; sCons[tid] = 0; }
  if (tid == 0) { sProgOut = 0; sConsOut = 0; }
  __syncthreads();   // the only barrier

  if (nt < LPW) {
    // ================= compute wave: layer l =================
    const int l = wgi * LPW + nt;
    const bool lastL = (l == NLAYER - 1);

    s16x8 Bh[4], Bl[4];
    float bq[4];
    #pragma unroll
    for (int q = 0; q < 4; ++q) {
      #pragma unroll
      for (int jj = 0; jj < 8; ++jj) {
        int k = quad * 8 + jj;
        float w = 0.f;
        if (j < HID) {
          int g = q * HID + j;
          if (k < HID)                      w = w_ih[(size_t)(l * G4 + g) * HID + k];
          else if (k >= 16 && k < 16 + HID) w = w_hh[(size_t)(l * G4 + g) * HID + (k - 16)];
        }
        short hi, lo; bf16split(w, hi, lo);
        Bh[q][jj] = hi; Bl[q][jj] = lo;
      }
      bq[q] = (j < HID) ? (b_ih[l * G4 + q * HID + j] + b_hh[l * G4 + q * HID + j]) : 0.f;
    }

    float cstate[4] = {0.f, 0.f, 0.f, 0.f};

    #pragma unroll 1
    for (int ci = 0; ci < NCH; ++ci) {
      const int slot  = ci & (RCL - 1);
      const int steps = (ci == NCH - 1) ? (T_SEQ - ci * CH) : CH;

      lspin_ge(&sProg[nt], ci + 1);
      if (ci + 1 - RCL > 0) {
        if (nt < 3) lspin_ge(&sCons[nt + 1], ci + 1 - RCL);
        else        lspin_ge(&sConsOut,      ci + 1 - RCL);
      }

      const short* xh = &sXP[nt][slot][0][0];
      const short* xl = &sXP[nt][slot][1][0];

      for (int s = 0; s < steps; ++s) {
        const short* ph = (quad < 2) ? &xh[s * 256 + j * 16 + quad * 8] : &sHh[nt][j][(quad - 2) * 8];
        const short* pl = (quad < 2) ? &xl[s * 256 + j * 16 + quad * 8] : &sHl[nt][j][(quad - 2) * 8];
        s16x8 Azh = *(const s16x8*)ph;
        s16x8 Azl = *(const s16x8*)pl;

        f32x4 acc[4];
        #pragma unroll
        for (int q = 0; q < 4; ++q) {
          f32x4 a = { bq[q], bq[q], bq[q], bq[q] };
          a = __builtin_amdgcn_mfma_f32_16x16x32_bf16(Azh, Bh[q], a, 0, 0, 0);
          a = __builtin_amdgcn_mfma_f32_16x16x32_bf16(Azh, Bl[q], a, 0, 0, 0);
          a = __builtin_amdgcn_mfma_f32_16x16x32_bf16(Azl, Bh[q], a, 0, 0, 0);
          acc[q] = a;
        }

        if (j < HID) {
          #pragma unroll
          for (int r = 0; r < 4; ++r) {
            float gi = acc[0][r], gf = acc[1][r], gg = acc[2][r], go = acc[3][r];
            float cn_ = sigm(gf) * cstate[r] + sigm(gi) * tanh_(gg);
            cstate[r] = cn_;
            float hn = sigm(go) * tanh_(cn_);
            short hi, lo; bf16split(hn, hi, lo);
            int br = quad * 4 + r;
            sHh[nt][br][j] = hi;
            sHl[nt][br][j] = lo;
            if (nt < 3) {
              sXP[nt + 1][slot][0][s * 256 + br * 16 + j] = hi;
              sXP[nt + 1][slot][1][s * 256 + br * 16 + j] = lo;
            } else if (!lastL) {
              short* so = (short*)&sOutR[slot][0];
              so[s * 256 + br * 16 + j]         = hi;   // hi-plane
              so[PLANE + s * 256 + br * 16 + j] = lo;   // lo-plane
            } else {
              sOutR[slot][s * WBH + br * HID + j] = __float_as_uint(hn);
            }
          }
        }
      }

      if (lane == 0) {
        __hip_atomic_store(&sCons[nt], ci + 1, __ATOMIC_RELEASE, __HIP_MEMORY_SCOPE_WORKGROUP);
        if (nt < 3)
          __hip_atomic_store(&sProg[nt + 1], ci + 1, __ATOMIC_RELEASE, __HIP_MEMORY_SCOPE_WORKGROUP);
        else
          __hip_atomic_store(&sProgOut, ci + 1, __ATOMIC_RELEASE, __HIP_MEMORY_SCOPE_WORKGROUP);
      }
    }
  } else {
    // ================= DMA wave =================
    const uint32_t* ringprev = ring + (size_t)(pp * NWGP + wgi - 1) * RING_U32_PER_WG;
    uint32_t*       ringmine = ring + (size_t)(pp * NWGP + wgi)     * RING_U32_PER_WG;
    const size_t    xbase    = (size_t)(pp * 16) * (T_SEQ * HID);

    // lane-linear maps for fp32 gather/scatter (26 = CH*WBH/64)
    int off0[26], xoff[26], aoff[26], sidx[26];
    #pragma unroll
    for (int k = 0; k < 26; ++k) {
      int i = lane + 64 * k;
      int s = i / WBH, r = i - s * WBH;
      int b16 = r / HID, jj = r - b16 * HID;
      off0[k] = s * 256 + b16 * 16 + jj;
      xoff[k] = b16 * (T_SEQ * HID) + s * HID + jj;
      aoff[k] = s * (BATCH * HID) + pp * WBH + r;
      sidx[k] = s;
    }

    int cin = 0, cout = 0;
    int cPrev = 0, cNext = 0;

    while (cin < NCH || cout < NCH) {
      // ---- readiness ----
      bool inok = (cin < NCH);
      if (inok && cin + 1 - RCL > 0 &&
          __hip_atomic_load(&sCons[0], __ATOMIC_ACQUIRE, __HIP_MEMORY_SCOPE_WORKGROUP) < cin + 1 - RCL)
        inok = false;
      if (inok && wgi > 0 && cPrev < cin + 1) {
        cPrev = __hip_atomic_load(flReadyPrev, __ATOMIC_RELAXED, __HIP_MEMORY_SCOPE_AGENT);
        if (cPrev < cin + 1) inok = false;
      }
      bool outok = (cout < NCH) &&
          (__hip_atomic_load(&sProgOut, __ATOMIC_ACQUIRE, __HIP_MEMORY_SCOPE_WORKGROUP) >= cout + 1);
      if (outok && !lastWG && cout + 1 - RC > 0 && cNext < cout + 1 - RC) {
        cNext = __hip_atomic_load(flProgNext, __ATOMIC_RELAXED, __HIP_MEMORY_SCOPE_AGENT);
        if (cNext < cout + 1 - RC) outok = false;
      }

      // ---- issue output stores first (drained by the shared vmcnt below) ----
      if (outok) {
        const int slot = cout & (RCL - 1);
        if (!lastWG) {
          uint32_t* dst = ringmine + (size_t)(cout & (RC - 1)) * CHUNK_U32;
          #pragma unroll
          for (int k = 0; k < 32; ++k)
            __hip_atomic_store(&dst[lane + 64 * k], sOutR[slot][lane + 64 * k],
                               __ATOMIC_RELAXED, __HIP_MEMORY_SCOPE_AGENT);
        } else {
          const int steps = (cout == NCH - 1) ? (T_SEQ - cout * CH) : CH;
          const size_t abase = (size_t)(cout * CH) * (BATCH * HID);
          #pragma unroll
          for (int k = 0; k < 26; ++k)
            if (sidx[k] < steps)
              act[abase + aoff[k]] = __uint_as_float(sOutR[slot][lane + 64 * k]);
        }
      }

      // ---- input: issue loads, restage (load-wait also drains the stores) ----
      if (inok) {
        const int slot = cin & (RCL - 1);
        if (wgi > 0) {
          const uint32_t* src = ringprev + (size_t)(cin & (RC - 1)) * CHUNK_U32;
          uint32_t v[32];
          #pragma unroll
          for (int k = 0; k < 32; ++k)
            v[k] = __hip_atomic_load(&src[lane + 64 * k], __ATOMIC_RELAXED, __HIP_MEMORY_SCOPE_AGENT);
          uint32_t* dst = (uint32_t*)&sXP[0][slot][0][0];
          #pragma unroll
          for (int k = 0; k < 32; ++k) dst[lane + 64 * k] = v[k];
        } else {
          const int steps = (cin == NCH - 1) ? (T_SEQ - cin * CH) : CH;
          float v[26];
          #pragma unroll
          for (int k = 0; k < 26; ++k)
            if (sidx[k] < steps)
              v[k] = xin[xbase + xoff[k] + (size_t)(cin * CH) * HID];
          #pragma unroll
          for (int k = 0; k < 26; ++k)
            if (sidx[k] < steps) {
              short hi, lo; bf16split(v[k], hi, lo);
              sXP[0][slot][0][off0[k]] = hi;
              sXP[0][slot][1][off0[k]] = lo;
            }
        }
      }

      if (inok || outok) {
        asm volatile("s_waitcnt vmcnt(0)" ::: "memory");
        if (lane == 0) {
          if (outok) {
            if (!lastWG)
              __hip_atomic_store(flReadySelf, cout + 1, __ATOMIC_RELAXED, __HIP_MEMORY_SCOPE_AGENT);
            __hip_atomic_store(&sConsOut, cout + 1, __ATOMIC_RELEASE, __HIP_MEMORY_SCOPE_WORKGROUP);
          }
          if (inok) {
            if (wgi > 0)
              __hip_atomic_store(flProgSelf, cin + 1, __ATOMIC_RELAXED, __HIP_MEMORY_SCOPE_AGENT);
            __hip_atomic_store(&sProg[0], cin + 1, __ATOMIC_RELEASE, __HIP_MEMORY_SCOPE_WORKGROUP);
          }
        }
        if (outok) ++cout;
        if (inok)  ++cin;
      } else {
        __builtin_amdgcn_s_sleep(1);
      }
    }
  }
}

__global__ __launch_bounds__(256) void linear_softmax(
    const float* __restrict__ act,    // [T][BATCH*HID]
    const float* __restrict__ w_lin,  // [NCLS][FEAT]
    const float* __restrict__ b_lin,
    float* __restrict__ out)          // [BATCH][NCLS]
{
  const int b   = blockIdx.x;
  const int tid = threadIdx.x;
  float accv[NCLS];
  #pragma unroll
  for (int c = 0; c < NCLS; ++c) accv[c] = 0.f;

  for (int i = tid; i < FEAT; i += 256) {
    int t = i / HID; int jj = i - t * HID;
    float a = act[(size_t)t * (BATCH * HID) + b * HID + jj];
    #pragma unroll
    for (int c = 0; c < NCLS; ++c)
      accv[c] += a * w_lin[(size_t)c * FEAT + i];
  }

  __shared__ float red[NCLS][256];
  #pragma unroll
  for (int c = 0; c < NCLS; ++c) red[c][tid] = accv[c];
  __syncthreads();
  for (int off = 128; off > 0; off >>= 1) {
    if (tid < off) {
      #pragma unroll
      for (int c = 0; c < NCLS; ++c) red[c][tid] += red[c][tid + off];
    }
    __syncthreads();
  }
  if (tid == 0) {
    float lg[NCLS]; float mx = -1e30f;
    #pragma unroll
    for (int c = 0; c < NCLS; ++c) { lg[c] = red[c][0] + b_lin[c]; mx = fmaxf(mx, lg[c]); }
    float sum = 0.f;
    #pragma unroll
    for (int c = 0; c < NCLS; ++c) { lg[c] = __expf(lg[c] - mx); sum += lg[c]; }
    float inv = 1.0f / sum;
    #pragma unroll
    for (int c = 0; c < NCLS; ++c) out[b * NCLS + c] = lg[c] * inv;
  }
}

extern "C" void kernel_launch(void* const* d_in, const int* in_sizes, int n_in,
                              void* d_out, int out_size, void* d_ws, size_t ws_size,
                              hipStream_t stream) {
  const float* xin  = (const float*)d_in[0];
  const float* wih  = (const float*)d_in[1];
  const float* whh  = (const float*)d_in[2];
  const float* bih  = (const float*)d_in[3];
  const float* bhh  = (const float*)d_in[4];
  const float* wlin = (const float*)d_in[5];
  const float* blin = (const float*)d_in[6];

  char*     ws    = (char*)d_ws;
  int*      flags = (int*)ws;
  uint32_t* ring  = (uint32_t*)(ws + FLAG_BYTES);
  float*    act   = (float*)(ws + FLAG_BYTES + RING_BYTES);

  lstm_pipeline<<<NPIPE * NWGP, 320, 0, stream>>>(xin, wih, whh, bih, bhh, flags, ring, act);
  linear_softmax<<<BATCH, 256, 0, stream>>>(act, wlin, blin, (float*)d_out);
}